// Round 3
// baseline (705.274 us; speedup 1.0000x reference)
//
#include <hip/hip_runtime.h>

// ---------------------------------------------------------------------------
// GCNEncoder: 3-layer GCN with symmetric norm and self-loops.
//   per layer: h = (x * out_norm) @ W ; agg = segsum(h[src], dst) + h (self)
//              out = agg * in_norm + b ; relu (layers 1,2)
// CSR build (by dst) -> aggregation is pure gather.
// R1: rank-based fill (atomic-free) + multi-block scan.
// R2: count_kernel 4 edges/thread (8 atomics in flight per lane — MLP theory);
//     agg edge-loop unroll x4; norm fused into scan1; single memset.
// ---------------------------------------------------------------------------

#define NFEAT 128

// 4 edges per thread, int4 vector loads. Fire-and-forget out_cnt atomics first,
// then the 4 returning in_cnt atomics (rank), one int4 rank store.
__global__ __launch_bounds__(256) void count_kernel(const int* __restrict__ src,
                                                    const int* __restrict__ dst,
                                                    int* __restrict__ out_cnt,
                                                    int* __restrict__ in_cnt,
                                                    int* __restrict__ rank, int E) {
    int i4 = blockIdx.x * 256 + threadIdx.x;
    int e0 = i4 * 4;
    if (e0 + 3 < E) {
        int4 s = ((const int4*)src)[i4];
        int4 d = ((const int4*)dst)[i4];
        atomicAdd(&out_cnt[s.x], 1);
        atomicAdd(&out_cnt[s.y], 1);
        atomicAdd(&out_cnt[s.z], 1);
        atomicAdd(&out_cnt[s.w], 1);
        int4 r;
        r.x = atomicAdd(&in_cnt[d.x], 1);
        r.y = atomicAdd(&in_cnt[d.y], 1);
        r.z = atomicAdd(&in_cnt[d.z], 1);
        r.w = atomicAdd(&in_cnt[d.w], 1);
        ((int4*)rank)[i4] = r;
    } else {
        for (int e = e0; e < E; ++e) {
            atomicAdd(&out_cnt[src[e]], 1);
            rank[e] = atomicAdd(&in_cnt[dst[e]], 1);
        }
    }
}

// --- multi-block exclusive scan over in_cnt; norms fused (reads out_cnt too) ---
__global__ __launch_bounds__(256) void scan1_kernel(const int* __restrict__ in_cnt,
                                                    const int* __restrict__ out_cnt,
                                                    float* __restrict__ out_norm,
                                                    float* __restrict__ in_norm,
                                                    int* __restrict__ excl,      // row_ptr[0..n)
                                                    int* __restrict__ blk_sum, int n) {
    const int tid = threadIdx.x, lane = tid & 63, wid = tid >> 6;  // 4 waves
    const int i = blockIdx.x * 256 + tid;
    int v = (i < n) ? in_cnt[i] : 0;
    if (i < n) {
        // +1 for self-loop; degree >= 1 so the reference clip is a no-op
        in_norm[i]  = rsqrtf((float)(v + 1));
        out_norm[i] = rsqrtf((float)(out_cnt[i] + 1));
    }
    int incl = v;
    #pragma unroll
    for (int off = 1; off < 64; off <<= 1) {
        int t = __shfl_up(incl, off, 64);
        if (lane >= off) incl += t;
    }
    __shared__ int ws[4];
    if (lane == 63) ws[wid] = incl;
    __syncthreads();
    int woff = 0;
    #pragma unroll
    for (int w = 0; w < 3; ++w) if (w < wid) woff += ws[w];
    if (i < n) excl[i] = woff + incl - v;
    if (tid == 0) blk_sum[blockIdx.x] = ws[0] + ws[1] + ws[2] + ws[3];
}

__global__ __launch_bounds__(512) void scan2_kernel(int* __restrict__ blk,
                                                    int* __restrict__ grand_total, int nb) {
    const int tid = threadIdx.x, lane = tid & 63, wid = tid >> 6;  // 8 waves
    int v = (tid < nb) ? blk[tid] : 0;
    int incl = v;
    #pragma unroll
    for (int off = 1; off < 64; off <<= 1) {
        int t = __shfl_up(incl, off, 64);
        if (lane >= off) incl += t;
    }
    __shared__ int ws[8];
    if (lane == 63) ws[wid] = incl;
    __syncthreads();
    int woff = 0;
    #pragma unroll
    for (int w = 0; w < 7; ++w) if (w < wid) woff += ws[w];
    int excl = woff + incl - v;
    if (tid < nb) blk[tid] = excl;
    if (tid == nb - 1) *grand_total = excl + v;   // row_ptr[n]
}

__global__ void scan3_kernel(int* __restrict__ excl, const int* __restrict__ blk, int n) {
    int i = blockIdx.x * 256 + threadIdx.x;
    if (i < n) excl[i] += blk[blockIdx.x];
}

// Atomic-free fill: position = row_ptr[dst] + rank(edge).
__global__ void fill_kernel(const int* __restrict__ src, const int* __restrict__ dst,
                            const int* __restrict__ rank, const int* __restrict__ row_ptr,
                            int* __restrict__ col_idx, int E) {
    int i = blockIdx.x * blockDim.x + threadIdx.x;
    if (i < E) {
        int d = dst[i];
        col_idx[row_ptr[d] + rank[i]] = src[i];
    }
}

// h[BM rows x BN] = (x * out_norm[:,None]) @ W,  K = 128 fixed, BK = 32.
// 256 threads, per-thread 8x(BN/32) register tile.
template <int BN>
__global__ __launch_bounds__(256) void gemm_norm_kernel(const float* __restrict__ x,
                                                        const float* __restrict__ W,
                                                        const float* __restrict__ out_norm,
                                                        float* __restrict__ h, int n_rows) {
    constexpr int BM = 64, BK = 32;
    constexpr int TN = BN / 32;                 // 4 (BN=128) or 2 (BN=64)
    __shared__ float xs[BK][BM + 4];            // transposed x tile
    __shared__ float wsh[BK][BN];

    const int tid  = threadIdx.x;
    const int row0 = blockIdx.x * BM;

    const int srow  = tid >> 2;                 // 0..63
    const int skoff = (tid & 3) * 8;            // 0,8,16,24
    const int grow  = row0 + srow;
    const bool rowok = (grow < n_rows);
    const float norm = rowok ? out_norm[grow] : 0.0f;
    const float* xrow = x + (size_t)grow * NFEAT;

    const int cg = tid & 31;                    // col group 0..31
    const int rg = tid >> 5;                    // row group 0..7 (8 rows each)

    float acc[8][TN];
    #pragma unroll
    for (int m = 0; m < 8; ++m)
        #pragma unroll
        for (int n = 0; n < TN; ++n) acc[m][n] = 0.0f;

    for (int k0 = 0; k0 < NFEAT; k0 += BK) {
        float v[8];
        if (rowok) {
            float4 p0 = *(const float4*)(xrow + k0 + skoff);
            float4 p1 = *(const float4*)(xrow + k0 + skoff + 4);
            v[0]=p0.x; v[1]=p0.y; v[2]=p0.z; v[3]=p0.w;
            v[4]=p1.x; v[5]=p1.y; v[6]=p1.z; v[7]=p1.w;
        } else {
            #pragma unroll
            for (int j = 0; j < 8; ++j) v[j] = 0.0f;
        }
        #pragma unroll
        for (int j = 0; j < 8; ++j) xs[skoff + j][srow] = v[j] * norm;

        constexpr int WLOAD = (BK * BN) / (256 * 4);  // float4s per thread
        #pragma unroll
        for (int t = 0; t < WLOAD; ++t) {
            int e  = (tid + t * 256) * 4;
            int kk = e / BN, cc = e % BN;
            float4 wv = *(const float4*)(W + (size_t)(k0 + kk) * BN + cc);
            *(float4*)&wsh[kk][cc] = wv;
        }
        __syncthreads();

        #pragma unroll
        for (int kk = 0; kk < BK; ++kk) {
            float a[8];
            float4 a0 = *(const float4*)&xs[kk][rg * 8];
            float4 a1 = *(const float4*)&xs[kk][rg * 8 + 4];
            a[0]=a0.x; a[1]=a0.y; a[2]=a0.z; a[3]=a0.w;
            a[4]=a1.x; a[5]=a1.y; a[6]=a1.z; a[7]=a1.w;
            float b[TN];
            if constexpr (TN == 4) {
                float4 bv = *(const float4*)&wsh[kk][cg * 4];
                b[0]=bv.x; b[1]=bv.y; b[2]=bv.z; b[3]=bv.w;
            } else {
                float2 bv = *(const float2*)&wsh[kk][cg * 2];
                b[0]=bv.x; b[1]=bv.y;
            }
            #pragma unroll
            for (int m = 0; m < 8; ++m)
                #pragma unroll
                for (int n = 0; n < TN; ++n) acc[m][n] += a[m] * b[n];
        }
        __syncthreads();
    }

    #pragma unroll
    for (int m = 0; m < 8; ++m) {
        int r = row0 + rg * 8 + m;
        if (r < n_rows) {
            if constexpr (TN == 4) {
                float4 o; o.x=acc[m][0]; o.y=acc[m][1]; o.z=acc[m][2]; o.w=acc[m][3];
                *(float4*)(h + (size_t)r * BN + cg * 4) = o;
            } else {
                float2 o; o.x=acc[m][0]; o.y=acc[m][1];
                *(float2*)(h + (size_t)r * BN + cg * 2) = o;
            }
        }
    }
}

// Gather aggregation + epilogue: out = (sum_{in-edges} h[src] + h[node]) * in_norm + b [, relu]
// R2: unroll x4 — 4 independent row-gathers in flight per sub-group.
template <int DOUT, bool RELU>
__global__ __launch_bounds__(256) void agg_kernel(const float* __restrict__ h,
                                                  const int* __restrict__ row_ptr,
                                                  const int* __restrict__ col_idx,
                                                  const float* __restrict__ in_norm,
                                                  const float* __restrict__ bias,
                                                  float* __restrict__ out, int n) {
    constexpr int TPN = DOUT / 4;      // threads per node (float4 each)
    constexpr int NPB = 256 / TPN;     // nodes per block
    const int tid  = threadIdx.x;
    const int sub  = tid / TPN;
    const int c    = (tid % TPN) * 4;
    const int node = blockIdx.x * NPB + sub;
    if (node >= n) return;

    float4 acc = *(const float4*)(h + (size_t)node * DOUT + c);   // self-loop message
    int e  = row_ptr[node];
    int e1 = row_ptr[node + 1];
    for (; e + 3 < e1; e += 4) {
        int s0 = col_idx[e];
        int s1 = col_idx[e + 1];
        int s2 = col_idx[e + 2];
        int s3 = col_idx[e + 3];
        float4 m0 = *(const float4*)(h + (size_t)s0 * DOUT + c);
        float4 m1 = *(const float4*)(h + (size_t)s1 * DOUT + c);
        float4 m2 = *(const float4*)(h + (size_t)s2 * DOUT + c);
        float4 m3 = *(const float4*)(h + (size_t)s3 * DOUT + c);
        acc.x += (m0.x + m1.x) + (m2.x + m3.x);
        acc.y += (m0.y + m1.y) + (m2.y + m3.y);
        acc.z += (m0.z + m1.z) + (m2.z + m3.z);
        acc.w += (m0.w + m1.w) + (m2.w + m3.w);
    }
    for (; e < e1; ++e) {
        int s0 = col_idx[e];
        float4 m0 = *(const float4*)(h + (size_t)s0 * DOUT + c);
        acc.x += m0.x; acc.y += m0.y; acc.z += m0.z; acc.w += m0.w;
    }
    float inn = in_norm[node];
    float4 bv = *(const float4*)(bias + c);
    float4 r;
    r.x = acc.x * inn + bv.x; r.y = acc.y * inn + bv.y;
    r.z = acc.z * inn + bv.z; r.w = acc.w * inn + bv.w;
    if (RELU) {
        r.x = fmaxf(r.x, 0.0f); r.y = fmaxf(r.y, 0.0f);
        r.z = fmaxf(r.z, 0.0f); r.w = fmaxf(r.w, 0.0f);
    }
    *(float4*)(out + (size_t)node * DOUT + c) = r;
}

extern "C" void kernel_launch(void* const* d_in, const int* in_sizes, int n_in,
                              void* d_out, int out_size, void* d_ws, size_t ws_size,
                              hipStream_t stream) {
    const float* feat = (const float*)d_in[0];
    const int*   src  = (const int*)d_in[1];
    const int*   dst  = (const int*)d_in[2];
    const float* W1   = (const float*)d_in[3];
    const float* b1   = (const float*)d_in[4];
    const float* W2   = (const float*)d_in[5];
    const float* b2   = (const float*)d_in[6];
    const float* W3   = (const float*)d_in[7];
    const float* b3   = (const float*)d_in[8];

    const int N = in_sizes[0] / NFEAT;   // 100000
    const int E = in_sizes[1];           // 1600000

    char* ws = (char*)d_ws;
    auto alloc = [&](size_t bytes) {
        char* p = ws;
        ws += (bytes + 255) & ~(size_t)255;
        return p;
    };
    int*   cnt2     = (int*)alloc((size_t)2 * N * 4);   // [out_cnt | in_cnt], one memset
    float* out_norm = (float*)alloc((size_t)N * 4);
    float* in_norm  = (float*)alloc((size_t)N * 4);
    int*   row_ptr  = (int*)alloc((size_t)(N + 1) * 4);
    int*   blk_sum  = (int*)alloc((size_t)1024 * 4);
    int*   col_idx  = (int*)alloc((size_t)E * 4);
    float* bufA     = (float*)alloc((size_t)N * NFEAT * 4);
    float* bufB     = (float*)alloc((size_t)N * NFEAT * 4);
    int*   out_cnt  = cnt2;
    int*   in_cnt   = cnt2 + N;
    int*   rank     = (int*)bufA;        // alias: bufA unused until layer-1 GEMM

    const int nb = (N + 255) / 256;      // scan blocking (391)

    // --- graph preprocessing (per call; inputs restored each call) ---
    hipMemsetAsync(cnt2, 0, (size_t)2 * N * 4, stream);
    count_kernel<<<(E / 4 + 255) / 256, 256, 0, stream>>>(src, dst, out_cnt, in_cnt, rank, E);
    scan1_kernel<<<nb, 256, 0, stream>>>(in_cnt, out_cnt, out_norm, in_norm, row_ptr, blk_sum, N);
    scan2_kernel<<<1, 512, 0, stream>>>(blk_sum, row_ptr + N, nb);
    scan3_kernel<<<nb, 256, 0, stream>>>(row_ptr, blk_sum, N);
    fill_kernel<<<(E + 255) / 256, 256, 0, stream>>>(src, dst, rank, row_ptr, col_idx, E);

    const int gb = (N + 63) / 64;
    // layer 1
    gemm_norm_kernel<128><<<gb, 256, 0, stream>>>(feat, W1, out_norm, bufA, N);
    agg_kernel<128, true><<<(N + 7) / 8, 256, 0, stream>>>(bufA, row_ptr, col_idx, in_norm, b1, bufB, N);
    // layer 2
    gemm_norm_kernel<128><<<gb, 256, 0, stream>>>(bufB, W2, out_norm, bufA, N);
    agg_kernel<128, true><<<(N + 7) / 8, 256, 0, stream>>>(bufA, row_ptr, col_idx, in_norm, b2, bufB, N);
    // layer 3 (no relu, write d_out)
    gemm_norm_kernel<64><<<gb, 256, 0, stream>>>(bufB, W3, out_norm, bufA, N);
    agg_kernel<64, false><<<(N + 15) / 16, 256, 0, stream>>>(bufA, row_ptr, col_idx, in_norm, b3,
                                                             (float*)d_out, N);
}

// Round 4
// 602.243 us; speedup vs baseline: 1.1711x; 1.1711x over previous
//
#include <hip/hip_runtime.h>

// ---------------------------------------------------------------------------
// GCNEncoder: 3-layer GCN with symmetric norm and self-loops.
//   per layer: h = (x * out_norm) @ W ; agg = segsum(h[src], dst) + h (self)
//              out = agg * in_norm + b ; relu (layers 1,2)
// CSR build (by dst) -> aggregation is pure gather.
// R1: rank-based fill + multi-block scan.
// R2: FAILED probe — device-atomic count is a ~20 G atomic/s write-through
//     floor (WRITE_SIZE = 3.2M x 32 B, rate insensitive to batching).
// R3: zero device atomics. LDS-atomic radix partition (bucket = node>>8):
//     hist -> scan -> scatter -> per-bucket CSR+norms. Atomics stay on-CU.
// ---------------------------------------------------------------------------

#define NFEAT 128
#define BBITS 8
#define BSZ 256                     // nodes per bucket
#define EPB 4096                    // edges per partition block (256 thr x 16)

// --- Pass 1: per-block LDS histograms over dst-buckets and src-buckets ---
__global__ __launch_bounds__(256) void hist_kernel(const int* __restrict__ src,
                                                   const int* __restrict__ dst,
                                                   int* __restrict__ histD,
                                                   int* __restrict__ histS,
                                                   int NB, int nblk, int E) {
    __shared__ int hd[512], hs[512];
    const int t = threadIdx.x, b = blockIdx.x;
    for (int u = t; u < 512; u += 256) { hd[u] = 0; hs[u] = 0; }
    __syncthreads();
    const int base4 = b * (EPB / 4);
    #pragma unroll
    for (int j = 0; j < 4; ++j) {
        int i4 = base4 + j * 256 + t;
        int e0 = i4 * 4;
        if (e0 + 3 < E) {
            int4 s = ((const int4*)src)[i4];
            int4 d = ((const int4*)dst)[i4];
            atomicAdd(&hs[s.x >> BBITS], 1); atomicAdd(&hs[s.y >> BBITS], 1);
            atomicAdd(&hs[s.z >> BBITS], 1); atomicAdd(&hs[s.w >> BBITS], 1);
            atomicAdd(&hd[d.x >> BBITS], 1); atomicAdd(&hd[d.y >> BBITS], 1);
            atomicAdd(&hd[d.z >> BBITS], 1); atomicAdd(&hd[d.w >> BBITS], 1);
        } else {
            for (int e = e0; e < E && e < e0 + 4; ++e) {
                atomicAdd(&hs[src[e] >> BBITS], 1);
                atomicAdd(&hd[dst[e] >> BBITS], 1);
            }
        }
    }
    __syncthreads();
    for (int u = t; u < NB; u += 256) {          // bucket-major layout [k*nblk + b]
        histD[u * nblk + b] = hd[u];
        histS[u * nblk + b] = hs[u];
    }
}

// --- multi-block exclusive scan (in-place capable) ---
__global__ __launch_bounds__(256) void scan1_kernel(const int* __restrict__ cnt,
                                                    int* __restrict__ excl,
                                                    int* __restrict__ blk_sum, int n) {
    const int tid = threadIdx.x, lane = tid & 63, wid = tid >> 6;  // 4 waves
    const int i = blockIdx.x * 256 + tid;
    int v = (i < n) ? cnt[i] : 0;
    int incl = v;
    #pragma unroll
    for (int off = 1; off < 64; off <<= 1) {
        int t = __shfl_up(incl, off, 64);
        if (lane >= off) incl += t;
    }
    __shared__ int ws[4];
    if (lane == 63) ws[wid] = incl;
    __syncthreads();
    int woff = 0;
    #pragma unroll
    for (int w = 0; w < 3; ++w) if (w < wid) woff += ws[w];
    if (i < n) excl[i] = woff + incl - v;
    if (tid == 0) blk_sum[blockIdx.x] = ws[0] + ws[1] + ws[2] + ws[3];
}

__global__ __launch_bounds__(1024) void scan2_kernel(int* __restrict__ blk,
                                                     int* __restrict__ grand_total, int nb) {
    const int tid = threadIdx.x, lane = tid & 63, wid = tid >> 6;  // 16 waves
    int v = (tid < nb) ? blk[tid] : 0;
    int incl = v;
    #pragma unroll
    for (int off = 1; off < 64; off <<= 1) {
        int t = __shfl_up(incl, off, 64);
        if (lane >= off) incl += t;
    }
    __shared__ int ws[16];
    if (lane == 63) ws[wid] = incl;
    __syncthreads();
    int woff = 0;
    #pragma unroll
    for (int w = 0; w < 15; ++w) if (w < wid) woff += ws[w];
    int excl = woff + incl - v;
    if (tid < nb) blk[tid] = excl;
    if (tid == nb - 1) *grand_total = excl + v;
}

__global__ void scan3_kernel(int* __restrict__ excl, const int* __restrict__ blk, int n) {
    int i = blockIdx.x * 256 + threadIdx.x;
    if (i < n) excl[i] += blk[blockIdx.x];
}

// --- Pass 2: scatter edges into bucket-partitioned arrays (LDS-atomic ranks) ---
__global__ __launch_bounds__(256) void scatter_kernel(const int* __restrict__ src,
                                                      const int* __restrict__ dst,
                                                      const int* __restrict__ offD,
                                                      const int* __restrict__ offS,
                                                      int* __restrict__ bsrc,
                                                      int* __restrict__ bdst,
                                                      int* __restrict__ ssrc,
                                                      int NB, int nblk, int E) {
    __shared__ int hd[512], hs[512], baseD[512], baseS[512];
    const int t = threadIdx.x, b = blockIdx.x;
    for (int u = t; u < 512; u += 256) { hd[u] = 0; hs[u] = 0; }
    for (int u = t; u < NB; u += 256) {
        baseD[u] = offD[u * nblk + b];
        baseS[u] = offS[u * nblk + b];
    }
    __syncthreads();
    const int base4 = b * (EPB / 4);
    #pragma unroll
    for (int j = 0; j < 4; ++j) {
        int i4 = base4 + j * 256 + t;
        int e0 = i4 * 4;
        if (e0 + 3 < E) {
            int4 s = ((const int4*)src)[i4];
            int4 d = ((const int4*)dst)[i4];
            int se[4] = {s.x, s.y, s.z, s.w};
            int de[4] = {d.x, d.y, d.z, d.w};
            #pragma unroll
            for (int q = 0; q < 4; ++q) {
                int kd = de[q] >> BBITS;
                int pos = baseD[kd] + atomicAdd(&hd[kd], 1);
                bdst[pos] = de[q];
                bsrc[pos] = se[q];
                int ks = se[q] >> BBITS;
                int posS = baseS[ks] + atomicAdd(&hs[ks], 1);
                ssrc[posS] = se[q];
            }
        } else {
            for (int e = e0; e < E && e < e0 + 4; ++e) {
                int sv = src[e], dv = dst[e];
                int kd = dv >> BBITS;
                int pos = baseD[kd] + atomicAdd(&hd[kd], 1);
                bdst[pos] = dv;
                bsrc[pos] = sv;
                int ks = sv >> BBITS;
                int posS = baseS[ks] + atomicAdd(&hs[ks], 1);
                ssrc[posS] = sv;
            }
        }
    }
}

// --- Pass 3: per-bucket CSR finalize + degrees + norms (all LDS) ---
__global__ __launch_bounds__(256) void bucket_kernel(const int* __restrict__ bsrc,
                                                     const int* __restrict__ bdst,
                                                     const int* __restrict__ ssrc,
                                                     const int* __restrict__ offD,
                                                     const int* __restrict__ offS,
                                                     int* __restrict__ row_ptr,
                                                     int* __restrict__ col_idx,
                                                     float* __restrict__ in_norm,
                                                     float* __restrict__ out_norm,
                                                     int N, int NB, int nblk, int E) {
    __shared__ int cnt[BSZ], scnt[BSZ], start[BSZ], off[BSZ];
    __shared__ int ws[4];
    const int k = blockIdx.x, t = threadIdx.x;
    const int node0 = k << BBITS;
    cnt[t] = 0; scnt[t] = 0; off[t] = 0;
    __syncthreads();
    const int bB = offD[k * nblk], bE = (k + 1 < NB) ? offD[(k + 1) * nblk] : E;
    const int sB = offS[k * nblk], sE = (k + 1 < NB) ? offS[(k + 1) * nblk] : E;
    for (int i = bB + t; i < bE; i += 256) atomicAdd(&cnt[bdst[i] - node0], 1);
    for (int i = sB + t; i < sE; i += 256) atomicAdd(&scnt[ssrc[i] - node0], 1);
    __syncthreads();
    // exclusive scan of cnt over 256 threads
    const int lane = t & 63, wid = t >> 6;
    int v = cnt[t];
    int incl = v;
    #pragma unroll
    for (int o = 1; o < 64; o <<= 1) {
        int x = __shfl_up(incl, o, 64);
        if (lane >= o) incl += x;
    }
    if (lane == 63) ws[wid] = incl;
    __syncthreads();
    int woff = 0;
    #pragma unroll
    for (int w = 0; w < 3; ++w) if (w < wid) woff += ws[w];
    start[t] = woff + incl - v;
    {
        int node = node0 + t;
        if (node < N) {
            row_ptr[node] = bB + start[t];
            in_norm[node]  = rsqrtf((float)(v + 1));          // +1 self-loop
            out_norm[node] = rsqrtf((float)(scnt[t] + 1));
        }
    }
    if (k == 0 && t == 0) row_ptr[N] = E;
    __syncthreads();
    for (int i = bB + t; i < bE; i += 256) {
        int local = bdst[i] - node0;
        int r = atomicAdd(&off[local], 1);
        col_idx[bB + start[local] + r] = bsrc[i];
    }
}

// h[BM rows x BN] = (x * out_norm[:,None]) @ W,  K = 128 fixed, BK = 32.
template <int BN>
__global__ __launch_bounds__(256) void gemm_norm_kernel(const float* __restrict__ x,
                                                        const float* __restrict__ W,
                                                        const float* __restrict__ out_norm,
                                                        float* __restrict__ h, int n_rows) {
    constexpr int BM = 64, BK = 32;
    constexpr int TN = BN / 32;                 // 4 (BN=128) or 2 (BN=64)
    __shared__ float xs[BK][BM + 4];            // transposed x tile
    __shared__ float wsh[BK][BN];

    const int tid  = threadIdx.x;
    const int row0 = blockIdx.x * BM;

    const int srow  = tid >> 2;                 // 0..63
    const int skoff = (tid & 3) * 8;            // 0,8,16,24
    const int grow  = row0 + srow;
    const bool rowok = (grow < n_rows);
    const float norm = rowok ? out_norm[grow] : 0.0f;
    const float* xrow = x + (size_t)grow * NFEAT;

    const int cg = tid & 31;                    // col group 0..31
    const int rg = tid >> 5;                    // row group 0..7 (8 rows each)

    float acc[8][TN];
    #pragma unroll
    for (int m = 0; m < 8; ++m)
        #pragma unroll
        for (int n = 0; n < TN; ++n) acc[m][n] = 0.0f;

    for (int k0 = 0; k0 < NFEAT; k0 += BK) {
        float v[8];
        if (rowok) {
            float4 p0 = *(const float4*)(xrow + k0 + skoff);
            float4 p1 = *(const float4*)(xrow + k0 + skoff + 4);
            v[0]=p0.x; v[1]=p0.y; v[2]=p0.z; v[3]=p0.w;
            v[4]=p1.x; v[5]=p1.y; v[6]=p1.z; v[7]=p1.w;
        } else {
            #pragma unroll
            for (int j = 0; j < 8; ++j) v[j] = 0.0f;
        }
        #pragma unroll
        for (int j = 0; j < 8; ++j) xs[skoff + j][srow] = v[j] * norm;

        constexpr int WLOAD = (BK * BN) / (256 * 4);  // float4s per thread
        #pragma unroll
        for (int t = 0; t < WLOAD; ++t) {
            int e  = (tid + t * 256) * 4;
            int kk = e / BN, cc = e % BN;
            float4 wv = *(const float4*)(W + (size_t)(k0 + kk) * BN + cc);
            *(float4*)&wsh[kk][cc] = wv;
        }
        __syncthreads();

        #pragma unroll
        for (int kk = 0; kk < BK; ++kk) {
            float a[8];
            float4 a0 = *(const float4*)&xs[kk][rg * 8];
            float4 a1 = *(const float4*)&xs[kk][rg * 8 + 4];
            a[0]=a0.x; a[1]=a0.y; a[2]=a0.z; a[3]=a0.w;
            a[4]=a1.x; a[5]=a1.y; a[6]=a1.z; a[7]=a1.w;
            float b[TN];
            if constexpr (TN == 4) {
                float4 bv = *(const float4*)&wsh[kk][cg * 4];
                b[0]=bv.x; b[1]=bv.y; b[2]=bv.z; b[3]=bv.w;
            } else {
                float2 bv = *(const float2*)&wsh[kk][cg * 2];
                b[0]=bv.x; b[1]=bv.y;
            }
            #pragma unroll
            for (int m = 0; m < 8; ++m)
                #pragma unroll
                for (int n = 0; n < TN; ++n) acc[m][n] += a[m] * b[n];
        }
        __syncthreads();
    }

    #pragma unroll
    for (int m = 0; m < 8; ++m) {
        int r = row0 + rg * 8 + m;
        if (r < n_rows) {
            if constexpr (TN == 4) {
                float4 o; o.x=acc[m][0]; o.y=acc[m][1]; o.z=acc[m][2]; o.w=acc[m][3];
                *(float4*)(h + (size_t)r * BN + cg * 4) = o;
            } else {
                float2 o; o.x=acc[m][0]; o.y=acc[m][1];
                *(float2*)(h + (size_t)r * BN + cg * 2) = o;
            }
        }
    }
}

// Gather aggregation + epilogue: out = (sum_in h[src] + h[node]) * in_norm + b [, relu]
template <int DOUT, bool RELU>
__global__ __launch_bounds__(256) void agg_kernel(const float* __restrict__ h,
                                                  const int* __restrict__ row_ptr,
                                                  const int* __restrict__ col_idx,
                                                  const float* __restrict__ in_norm,
                                                  const float* __restrict__ bias,
                                                  float* __restrict__ out, int n) {
    constexpr int TPN = DOUT / 4;      // threads per node (float4 each)
    constexpr int NPB = 256 / TPN;     // nodes per block
    const int tid  = threadIdx.x;
    const int sub  = tid / TPN;
    const int c    = (tid % TPN) * 4;
    const int node = blockIdx.x * NPB + sub;
    if (node >= n) return;

    float4 acc = *(const float4*)(h + (size_t)node * DOUT + c);   // self-loop message
    int e  = row_ptr[node];
    int e1 = row_ptr[node + 1];
    for (; e + 3 < e1; e += 4) {
        int s0 = col_idx[e];
        int s1 = col_idx[e + 1];
        int s2 = col_idx[e + 2];
        int s3 = col_idx[e + 3];
        float4 m0 = *(const float4*)(h + (size_t)s0 * DOUT + c);
        float4 m1 = *(const float4*)(h + (size_t)s1 * DOUT + c);
        float4 m2 = *(const float4*)(h + (size_t)s2 * DOUT + c);
        float4 m3 = *(const float4*)(h + (size_t)s3 * DOUT + c);
        acc.x += (m0.x + m1.x) + (m2.x + m3.x);
        acc.y += (m0.y + m1.y) + (m2.y + m3.y);
        acc.z += (m0.z + m1.z) + (m2.z + m3.z);
        acc.w += (m0.w + m1.w) + (m2.w + m3.w);
    }
    for (; e < e1; ++e) {
        int s0 = col_idx[e];
        float4 m0 = *(const float4*)(h + (size_t)s0 * DOUT + c);
        acc.x += m0.x; acc.y += m0.y; acc.z += m0.z; acc.w += m0.w;
    }
    float inn = in_norm[node];
    float4 bv = *(const float4*)(bias + c);
    float4 r;
    r.x = acc.x * inn + bv.x; r.y = acc.y * inn + bv.y;
    r.z = acc.z * inn + bv.z; r.w = acc.w * inn + bv.w;
    if (RELU) {
        r.x = fmaxf(r.x, 0.0f); r.y = fmaxf(r.y, 0.0f);
        r.z = fmaxf(r.z, 0.0f); r.w = fmaxf(r.w, 0.0f);
    }
    *(float4*)(out + (size_t)node * DOUT + c) = r;
}

extern "C" void kernel_launch(void* const* d_in, const int* in_sizes, int n_in,
                              void* d_out, int out_size, void* d_ws, size_t ws_size,
                              hipStream_t stream) {
    const float* feat = (const float*)d_in[0];
    const int*   src  = (const int*)d_in[1];
    const int*   dst  = (const int*)d_in[2];
    const float* W1   = (const float*)d_in[3];
    const float* b1   = (const float*)d_in[4];
    const float* W2   = (const float*)d_in[5];
    const float* b2   = (const float*)d_in[6];
    const float* W3   = (const float*)d_in[7];
    const float* b3   = (const float*)d_in[8];

    const int N = in_sizes[0] / NFEAT;   // 100000
    const int E = in_sizes[1];           // 1600000

    const int NB   = (N + BSZ - 1) / BSZ;        // 391 buckets
    const int nblk = (E + EPB - 1) / EPB;        // 391 partition blocks
    const int nh   = NB * nblk;                  // hist elements (152,881)
    const int nsb  = (nh + 255) / 256;           // scan blocks (598 <= 1024)

    char* ws = (char*)d_ws;
    auto alloc = [&](size_t bytes) {
        char* p = ws;
        ws += (bytes + 255) & ~(size_t)255;
        return p;
    };
    float* out_norm = (float*)alloc((size_t)N * 4);
    float* in_norm  = (float*)alloc((size_t)N * 4);
    int*   row_ptr  = (int*)alloc((size_t)(N + 1) * 4);
    int*   histD    = (int*)alloc((size_t)nh * 4);
    int*   histS    = (int*)alloc((size_t)nh * 4);
    int*   blk_sum  = (int*)alloc((size_t)1024 * 4);
    int*   scratch  = (int*)alloc((size_t)16 * 4);
    int*   col_idx  = (int*)alloc((size_t)E * 4);
    float* bufA     = (float*)alloc((size_t)N * NFEAT * 4);
    float* bufB     = (float*)alloc((size_t)N * NFEAT * 4);
    // partition arrays alias bufA (unused until layer-1 GEMM): 3*E ints = 19.2 MB < 51.2 MB
    int*   bdst     = (int*)bufA;
    int*   bsrc     = (int*)bufA + E;
    int*   ssrc     = (int*)bufA + 2 * (size_t)E;

    // --- CSR build: hist -> scan(D) -> scan(S) -> scatter -> bucket ---
    hist_kernel<<<nblk, 256, 0, stream>>>(src, dst, histD, histS, NB, nblk, E);
    scan1_kernel<<<nsb, 256, 0, stream>>>(histD, histD, blk_sum, nh);
    scan2_kernel<<<1, 1024, 0, stream>>>(blk_sum, scratch, nsb);
    scan3_kernel<<<nsb, 256, 0, stream>>>(histD, blk_sum, nh);
    scan1_kernel<<<nsb, 256, 0, stream>>>(histS, histS, blk_sum, nh);
    scan2_kernel<<<1, 1024, 0, stream>>>(blk_sum, scratch, nsb);
    scan3_kernel<<<nsb, 256, 0, stream>>>(histS, blk_sum, nh);
    scatter_kernel<<<nblk, 256, 0, stream>>>(src, dst, histD, histS, bsrc, bdst, ssrc, NB, nblk, E);
    bucket_kernel<<<NB, 256, 0, stream>>>(bsrc, bdst, ssrc, histD, histS, row_ptr, col_idx,
                                          in_norm, out_norm, N, NB, nblk, E);

    const int gb = (N + 63) / 64;
    // layer 1
    gemm_norm_kernel<128><<<gb, 256, 0, stream>>>(feat, W1, out_norm, bufA, N);
    agg_kernel<128, true><<<(N + 7) / 8, 256, 0, stream>>>(bufA, row_ptr, col_idx, in_norm, b1, bufB, N);
    // layer 2
    gemm_norm_kernel<128><<<gb, 256, 0, stream>>>(bufB, W2, out_norm, bufA, N);
    agg_kernel<128, true><<<(N + 7) / 8, 256, 0, stream>>>(bufA, row_ptr, col_idx, in_norm, b2, bufB, N);
    // layer 3 (no relu, write d_out)
    gemm_norm_kernel<64><<<gb, 256, 0, stream>>>(bufB, W3, out_norm, bufA, N);
    agg_kernel<64, false><<<(N + 15) / 16, 256, 0, stream>>>(bufA, row_ptr, col_idx, in_norm, b3,
                                                             (float*)d_out, N);
}

// Round 5
// 463.231 us; speedup vs baseline: 1.5225x; 1.3001x over previous
//
#include <hip/hip_runtime.h>
#include <hip/hip_fp16.h>

// ---------------------------------------------------------------------------
// GCNEncoder: 3-layer GCN with symmetric norm and self-loops.
//   per layer: h = (x * out_norm) @ W ; agg = segsum(h[src], dst) + h (self)
//              out = agg * in_norm + b ; relu (layers 1,2)
// CSR build (by dst) -> aggregation is pure gather.
// R2: FAILED probe — device-atomic count has a ~20 G atomic/s write-through
//     floor. R3: LDS-atomic radix partition (zero device atomics).
// R4: inter-layer feature tables in fp16 — agg gathers 256 B rows instead of
//     512 B (table 25.6 MB ~ L2-resident). Compute stays fp32.
// ---------------------------------------------------------------------------

#define NFEAT 128
#define BBITS 8
#define BSZ 256                     // nodes per bucket
#define EPB 4096                    // edges per partition block (256 thr x 16)

union H8 { float4 f4; __half2 h2[4]; };   // 8 halves = 16 B
union H4 { float2 f2; __half2 h2[2]; };   // 4 halves = 8 B

// --- Pass 1: per-block LDS histograms over dst-buckets and src-buckets ---
__global__ __launch_bounds__(256) void hist_kernel(const int* __restrict__ src,
                                                   const int* __restrict__ dst,
                                                   int* __restrict__ histD,
                                                   int* __restrict__ histS,
                                                   int NB, int nblk, int E) {
    __shared__ int hd[512], hs[512];
    const int t = threadIdx.x, b = blockIdx.x;
    for (int u = t; u < 512; u += 256) { hd[u] = 0; hs[u] = 0; }
    __syncthreads();
    const int base4 = b * (EPB / 4);
    #pragma unroll
    for (int j = 0; j < 4; ++j) {
        int i4 = base4 + j * 256 + t;
        int e0 = i4 * 4;
        if (e0 + 3 < E) {
            int4 s = ((const int4*)src)[i4];
            int4 d = ((const int4*)dst)[i4];
            atomicAdd(&hs[s.x >> BBITS], 1); atomicAdd(&hs[s.y >> BBITS], 1);
            atomicAdd(&hs[s.z >> BBITS], 1); atomicAdd(&hs[s.w >> BBITS], 1);
            atomicAdd(&hd[d.x >> BBITS], 1); atomicAdd(&hd[d.y >> BBITS], 1);
            atomicAdd(&hd[d.z >> BBITS], 1); atomicAdd(&hd[d.w >> BBITS], 1);
        } else {
            for (int e = e0; e < E && e < e0 + 4; ++e) {
                atomicAdd(&hs[src[e] >> BBITS], 1);
                atomicAdd(&hd[dst[e] >> BBITS], 1);
            }
        }
    }
    __syncthreads();
    for (int u = t; u < NB; u += 256) {          // bucket-major layout [k*nblk + b]
        histD[u * nblk + b] = hd[u];
        histS[u * nblk + b] = hs[u];
    }
}

// --- multi-block exclusive scan (in-place capable) ---
__global__ __launch_bounds__(256) void scan1_kernel(const int* __restrict__ cnt,
                                                    int* __restrict__ excl,
                                                    int* __restrict__ blk_sum, int n) {
    const int tid = threadIdx.x, lane = tid & 63, wid = tid >> 6;  // 4 waves
    const int i = blockIdx.x * 256 + tid;
    int v = (i < n) ? cnt[i] : 0;
    int incl = v;
    #pragma unroll
    for (int off = 1; off < 64; off <<= 1) {
        int t = __shfl_up(incl, off, 64);
        if (lane >= off) incl += t;
    }
    __shared__ int ws[4];
    if (lane == 63) ws[wid] = incl;
    __syncthreads();
    int woff = 0;
    #pragma unroll
    for (int w = 0; w < 3; ++w) if (w < wid) woff += ws[w];
    if (i < n) excl[i] = woff + incl - v;
    if (tid == 0) blk_sum[blockIdx.x] = ws[0] + ws[1] + ws[2] + ws[3];
}

__global__ __launch_bounds__(1024) void scan2_kernel(int* __restrict__ blk,
                                                     int* __restrict__ grand_total, int nb) {
    const int tid = threadIdx.x, lane = tid & 63, wid = tid >> 6;  // 16 waves
    int v = (tid < nb) ? blk[tid] : 0;
    int incl = v;
    #pragma unroll
    for (int off = 1; off < 64; off <<= 1) {
        int t = __shfl_up(incl, off, 64);
        if (lane >= off) incl += t;
    }
    __shared__ int ws[16];
    if (lane == 63) ws[wid] = incl;
    __syncthreads();
    int woff = 0;
    #pragma unroll
    for (int w = 0; w < 15; ++w) if (w < wid) woff += ws[w];
    int excl = woff + incl - v;
    if (tid < nb) blk[tid] = excl;
    if (tid == nb - 1) *grand_total = excl + v;
}

__global__ void scan3_kernel(int* __restrict__ excl, const int* __restrict__ blk, int n) {
    int i = blockIdx.x * 256 + threadIdx.x;
    if (i < n) excl[i] += blk[blockIdx.x];
}

// --- Pass 2: scatter edges into bucket-partitioned arrays (LDS-atomic ranks) ---
__global__ __launch_bounds__(256) void scatter_kernel(const int* __restrict__ src,
                                                      const int* __restrict__ dst,
                                                      const int* __restrict__ offD,
                                                      const int* __restrict__ offS,
                                                      int* __restrict__ bsrc,
                                                      int* __restrict__ bdst,
                                                      int* __restrict__ ssrc,
                                                      int NB, int nblk, int E) {
    __shared__ int hd[512], hs[512], baseD[512], baseS[512];
    const int t = threadIdx.x, b = blockIdx.x;
    for (int u = t; u < 512; u += 256) { hd[u] = 0; hs[u] = 0; }
    for (int u = t; u < NB; u += 256) {
        baseD[u] = offD[u * nblk + b];
        baseS[u] = offS[u * nblk + b];
    }
    __syncthreads();
    const int base4 = b * (EPB / 4);
    #pragma unroll
    for (int j = 0; j < 4; ++j) {
        int i4 = base4 + j * 256 + t;
        int e0 = i4 * 4;
        if (e0 + 3 < E) {
            int4 s = ((const int4*)src)[i4];
            int4 d = ((const int4*)dst)[i4];
            int se[4] = {s.x, s.y, s.z, s.w};
            int de[4] = {d.x, d.y, d.z, d.w};
            #pragma unroll
            for (int q = 0; q < 4; ++q) {
                int kd = de[q] >> BBITS;
                int pos = baseD[kd] + atomicAdd(&hd[kd], 1);
                bdst[pos] = de[q];
                bsrc[pos] = se[q];
                int ks = se[q] >> BBITS;
                int posS = baseS[ks] + atomicAdd(&hs[ks], 1);
                ssrc[posS] = se[q];
            }
        } else {
            for (int e = e0; e < E && e < e0 + 4; ++e) {
                int sv = src[e], dv = dst[e];
                int kd = dv >> BBITS;
                int pos = baseD[kd] + atomicAdd(&hd[kd], 1);
                bdst[pos] = dv;
                bsrc[pos] = sv;
                int ks = sv >> BBITS;
                int posS = baseS[ks] + atomicAdd(&hs[ks], 1);
                ssrc[posS] = sv;
            }
        }
    }
}

// --- Pass 3: per-bucket CSR finalize + degrees + norms (all LDS) ---
__global__ __launch_bounds__(256) void bucket_kernel(const int* __restrict__ bsrc,
                                                     const int* __restrict__ bdst,
                                                     const int* __restrict__ ssrc,
                                                     const int* __restrict__ offD,
                                                     const int* __restrict__ offS,
                                                     int* __restrict__ row_ptr,
                                                     int* __restrict__ col_idx,
                                                     float* __restrict__ in_norm,
                                                     float* __restrict__ out_norm,
                                                     int N, int NB, int nblk, int E) {
    __shared__ int cnt[BSZ], scnt[BSZ], start[BSZ], off[BSZ];
    __shared__ int ws[4];
    const int k = blockIdx.x, t = threadIdx.x;
    const int node0 = k << BBITS;
    cnt[t] = 0; scnt[t] = 0; off[t] = 0;
    __syncthreads();
    const int bB = offD[k * nblk], bE = (k + 1 < NB) ? offD[(k + 1) * nblk] : E;
    const int sB = offS[k * nblk], sE = (k + 1 < NB) ? offS[(k + 1) * nblk] : E;
    for (int i = bB + t; i < bE; i += 256) atomicAdd(&cnt[bdst[i] - node0], 1);
    for (int i = sB + t; i < sE; i += 256) atomicAdd(&scnt[ssrc[i] - node0], 1);
    __syncthreads();
    const int lane = t & 63, wid = t >> 6;
    int v = cnt[t];
    int incl = v;
    #pragma unroll
    for (int o = 1; o < 64; o <<= 1) {
        int x = __shfl_up(incl, o, 64);
        if (lane >= o) incl += x;
    }
    if (lane == 63) ws[wid] = incl;
    __syncthreads();
    int woff = 0;
    #pragma unroll
    for (int w = 0; w < 3; ++w) if (w < wid) woff += ws[w];
    start[t] = woff + incl - v;
    {
        int node = node0 + t;
        if (node < N) {
            row_ptr[node] = bB + start[t];
            in_norm[node]  = rsqrtf((float)(v + 1));          // +1 self-loop
            out_norm[node] = rsqrtf((float)(scnt[t] + 1));
        }
    }
    if (k == 0 && t == 0) row_ptr[N] = E;
    __syncthreads();
    for (int i = bB + t; i < bE; i += 256) {
        int local = bdst[i] - node0;
        int r = atomicAdd(&off[local], 1);
        col_idx[bB + start[local] + r] = bsrc[i];
    }
}

// h[BM rows x BN] = (x * out_norm[:,None]) @ W,  K = 128 fixed, BK = 32.
// XT = float (layer 1) or __half (layers 2-3). Output h is __half.
template <int BN, typename XT>
__global__ __launch_bounds__(256) void gemm_norm_kernel(const XT* __restrict__ x,
                                                        const float* __restrict__ W,
                                                        const float* __restrict__ out_norm,
                                                        __half* __restrict__ h, int n_rows) {
    constexpr int BM = 64, BK = 32;
    constexpr int TN = BN / 32;                 // 4 (BN=128) or 2 (BN=64)
    __shared__ float xs[BK][BM + 4];            // transposed x tile
    __shared__ float wsh[BK][BN];

    const int tid  = threadIdx.x;
    const int row0 = blockIdx.x * BM;

    const int srow  = tid >> 2;                 // 0..63
    const int skoff = (tid & 3) * 8;            // 0,8,16,24
    const int grow  = row0 + srow;
    const bool rowok = (grow < n_rows);
    const float norm = rowok ? out_norm[grow] : 0.0f;
    const XT* xrow = x + (size_t)grow * NFEAT;

    const int cg = tid & 31;                    // col group 0..31
    const int rg = tid >> 5;                    // row group 0..7 (8 rows each)

    float acc[8][TN];
    #pragma unroll
    for (int m = 0; m < 8; ++m)
        #pragma unroll
        for (int n = 0; n < TN; ++n) acc[m][n] = 0.0f;

    for (int k0 = 0; k0 < NFEAT; k0 += BK) {
        float v[8];
        if (rowok) {
            if constexpr (sizeof(XT) == 4) {
                float4 p0 = *(const float4*)((const float*)xrow + k0 + skoff);
                float4 p1 = *(const float4*)((const float*)xrow + k0 + skoff + 4);
                v[0]=p0.x; v[1]=p0.y; v[2]=p0.z; v[3]=p0.w;
                v[4]=p1.x; v[5]=p1.y; v[6]=p1.z; v[7]=p1.w;
            } else {
                H8 u; u.f4 = *(const float4*)((const __half*)xrow + k0 + skoff);
                #pragma unroll
                for (int q = 0; q < 4; ++q) {
                    float2 p = __half22float2(u.h2[q]);
                    v[q * 2] = p.x; v[q * 2 + 1] = p.y;
                }
            }
        } else {
            #pragma unroll
            for (int j = 0; j < 8; ++j) v[j] = 0.0f;
        }
        #pragma unroll
        for (int j = 0; j < 8; ++j) xs[skoff + j][srow] = v[j] * norm;

        constexpr int WLOAD = (BK * BN) / (256 * 4);  // float4s per thread
        #pragma unroll
        for (int t = 0; t < WLOAD; ++t) {
            int e  = (tid + t * 256) * 4;
            int kk = e / BN, cc = e % BN;
            float4 wv = *(const float4*)(W + (size_t)(k0 + kk) * BN + cc);
            *(float4*)&wsh[kk][cc] = wv;
        }
        __syncthreads();

        #pragma unroll
        for (int kk = 0; kk < BK; ++kk) {
            float a[8];
            float4 a0 = *(const float4*)&xs[kk][rg * 8];
            float4 a1 = *(const float4*)&xs[kk][rg * 8 + 4];
            a[0]=a0.x; a[1]=a0.y; a[2]=a0.z; a[3]=a0.w;
            a[4]=a1.x; a[5]=a1.y; a[6]=a1.z; a[7]=a1.w;
            float b[TN];
            if constexpr (TN == 4) {
                float4 bv = *(const float4*)&wsh[kk][cg * 4];
                b[0]=bv.x; b[1]=bv.y; b[2]=bv.z; b[3]=bv.w;
            } else {
                float2 bv = *(const float2*)&wsh[kk][cg * 2];
                b[0]=bv.x; b[1]=bv.y;
            }
            #pragma unroll
            for (int m = 0; m < 8; ++m)
                #pragma unroll
                for (int n = 0; n < TN; ++n) acc[m][n] += a[m] * b[n];
        }
        __syncthreads();
    }

    #pragma unroll
    for (int m = 0; m < 8; ++m) {
        int r = row0 + rg * 8 + m;
        if (r < n_rows) {
            if constexpr (TN == 4) {
                H4 o;
                o.h2[0] = __floats2half2_rn(acc[m][0], acc[m][1]);
                o.h2[1] = __floats2half2_rn(acc[m][2], acc[m][3]);
                *(float2*)(h + (size_t)r * BN + cg * 4) = o.f2;
            } else {
                __half2 o = __floats2half2_rn(acc[m][0], acc[m][1]);
                *(__half2*)(h + (size_t)r * BN + cg * 2) = o;
            }
        }
    }
}

// Gather aggregation + epilogue: out = (sum_in h[src] + h[node]) * in_norm + b [, relu]
// h is fp16 (256 B rows for DOUT=128); accumulate fp32; OutT = __half or float.
template <int DOUT, bool RELU, typename OutT>
__global__ __launch_bounds__(256) void agg_kernel(const __half* __restrict__ h,
                                                  const int* __restrict__ row_ptr,
                                                  const int* __restrict__ col_idx,
                                                  const float* __restrict__ in_norm,
                                                  const float* __restrict__ bias,
                                                  OutT* __restrict__ out, int n) {
    constexpr int TPN = DOUT / 8;      // threads per node (8 halves = 16 B each)
    constexpr int NPB = 256 / TPN;     // nodes per block
    const int tid  = threadIdx.x;
    const int sub  = tid / TPN;
    const int c    = (tid % TPN) * 8;
    const int node = blockIdx.x * NPB + sub;
    if (node >= n) return;

    float acc[8];
    {
        H8 u; u.f4 = *(const float4*)(h + (size_t)node * DOUT + c);  // self-loop
        #pragma unroll
        for (int q = 0; q < 4; ++q) {
            float2 p = __half22float2(u.h2[q]);
            acc[q * 2] = p.x; acc[q * 2 + 1] = p.y;
        }
    }
    int e  = row_ptr[node];
    int e1 = row_ptr[node + 1];
    for (; e + 3 < e1; e += 4) {
        int s0 = col_idx[e], s1 = col_idx[e + 1], s2 = col_idx[e + 2], s3 = col_idx[e + 3];
        H8 u0, u1, u2, u3;
        u0.f4 = *(const float4*)(h + (size_t)s0 * DOUT + c);
        u1.f4 = *(const float4*)(h + (size_t)s1 * DOUT + c);
        u2.f4 = *(const float4*)(h + (size_t)s2 * DOUT + c);
        u3.f4 = *(const float4*)(h + (size_t)s3 * DOUT + c);
        #pragma unroll
        for (int q = 0; q < 4; ++q) {
            float2 p0 = __half22float2(u0.h2[q]);
            float2 p1 = __half22float2(u1.h2[q]);
            float2 p2 = __half22float2(u2.h2[q]);
            float2 p3 = __half22float2(u3.h2[q]);
            acc[q * 2]     += (p0.x + p1.x) + (p2.x + p3.x);
            acc[q * 2 + 1] += (p0.y + p1.y) + (p2.y + p3.y);
        }
    }
    for (; e < e1; ++e) {
        int s0 = col_idx[e];
        H8 u0; u0.f4 = *(const float4*)(h + (size_t)s0 * DOUT + c);
        #pragma unroll
        for (int q = 0; q < 4; ++q) {
            float2 p0 = __half22float2(u0.h2[q]);
            acc[q * 2] += p0.x; acc[q * 2 + 1] += p0.y;
        }
    }
    float inn = in_norm[node];
    float r[8];
    #pragma unroll
    for (int q = 0; q < 8; ++q) {
        r[q] = acc[q] * inn + bias[c + q];
        if (RELU) r[q] = fmaxf(r[q], 0.0f);
    }
    if constexpr (sizeof(OutT) == 2) {
        H8 o;
        #pragma unroll
        for (int q = 0; q < 4; ++q) o.h2[q] = __floats2half2_rn(r[q * 2], r[q * 2 + 1]);
        *(float4*)((__half*)out + (size_t)node * DOUT + c) = o.f4;
    } else {
        float4 o0, o1;
        o0.x=r[0]; o0.y=r[1]; o0.z=r[2]; o0.w=r[3];
        o1.x=r[4]; o1.y=r[5]; o1.z=r[6]; o1.w=r[7];
        *(float4*)((float*)out + (size_t)node * DOUT + c)     = o0;
        *(float4*)((float*)out + (size_t)node * DOUT + c + 4) = o1;
    }
}

extern "C" void kernel_launch(void* const* d_in, const int* in_sizes, int n_in,
                              void* d_out, int out_size, void* d_ws, size_t ws_size,
                              hipStream_t stream) {
    const float* feat = (const float*)d_in[0];
    const int*   src  = (const int*)d_in[1];
    const int*   dst  = (const int*)d_in[2];
    const float* W1   = (const float*)d_in[3];
    const float* b1   = (const float*)d_in[4];
    const float* W2   = (const float*)d_in[5];
    const float* b2   = (const float*)d_in[6];
    const float* W3   = (const float*)d_in[7];
    const float* b3   = (const float*)d_in[8];

    const int N = in_sizes[0] / NFEAT;   // 100000
    const int E = in_sizes[1];           // 1600000

    const int NB   = (N + BSZ - 1) / BSZ;        // 391 buckets
    const int nblk = (E + EPB - 1) / EPB;        // 391 partition blocks
    const int nh   = NB * nblk;                  // hist elements (152,881)
    const int nsb  = (nh + 255) / 256;           // scan blocks (598 <= 1024)

    char* ws = (char*)d_ws;
    auto alloc = [&](size_t bytes) {
        char* p = ws;
        ws += (bytes + 255) & ~(size_t)255;
        return p;
    };
    float* out_norm = (float*)alloc((size_t)N * 4);
    float* in_norm  = (float*)alloc((size_t)N * 4);
    int*   row_ptr  = (int*)alloc((size_t)(N + 1) * 4);
    int*   histD    = (int*)alloc((size_t)nh * 4);
    int*   histS    = (int*)alloc((size_t)nh * 4);
    int*   blk_sum  = (int*)alloc((size_t)1024 * 4);
    int*   scratch  = (int*)alloc((size_t)16 * 4);
    int*   col_idx  = (int*)alloc((size_t)E * 4);
    // hA region also hosts the 3 partition arrays (3*E*4 = 19.2 MB <= 25.6 MB)
    __half* hA      = (__half*)alloc((size_t)N * NFEAT * 2);
    __half* hB      = (__half*)alloc((size_t)N * NFEAT * 2);
    int*   bdst     = (int*)hA;
    int*   bsrc     = (int*)hA + E;
    int*   ssrc     = (int*)hA + 2 * (size_t)E;

    // --- CSR build: hist -> scan(D) -> scan(S) -> scatter -> bucket ---
    hist_kernel<<<nblk, 256, 0, stream>>>(src, dst, histD, histS, NB, nblk, E);
    scan1_kernel<<<nsb, 256, 0, stream>>>(histD, histD, blk_sum, nh);
    scan2_kernel<<<1, 1024, 0, stream>>>(blk_sum, scratch, nsb);
    scan3_kernel<<<nsb, 256, 0, stream>>>(histD, blk_sum, nh);
    scan1_kernel<<<nsb, 256, 0, stream>>>(histS, histS, blk_sum, nh);
    scan2_kernel<<<1, 1024, 0, stream>>>(blk_sum, scratch, nsb);
    scan3_kernel<<<nsb, 256, 0, stream>>>(histS, blk_sum, nh);
    scatter_kernel<<<nblk, 256, 0, stream>>>(src, dst, histD, histS, bsrc, bdst, ssrc, NB, nblk, E);
    bucket_kernel<<<NB, 256, 0, stream>>>(bsrc, bdst, ssrc, histD, histS, row_ptr, col_idx,
                                          in_norm, out_norm, N, NB, nblk, E);

    const int gb = (N + 63) / 64;
    // layer 1 (x fp32 -> h fp16)
    gemm_norm_kernel<128, float><<<gb, 256, 0, stream>>>(feat, W1, out_norm, hA, N);
    agg_kernel<128, true, __half><<<(N + 15) / 16, 256, 0, stream>>>(hA, row_ptr, col_idx,
                                                                     in_norm, b1, hB, N);
    // layer 2 (fp16 -> fp16)
    gemm_norm_kernel<128, __half><<<gb, 256, 0, stream>>>(hB, W2, out_norm, hA, N);
    agg_kernel<128, true, __half><<<(N + 15) / 16, 256, 0, stream>>>(hA, row_ptr, col_idx,
                                                                     in_norm, b2, hB, N);
    // layer 3 (fp16 -> fp32 d_out, no relu)
    gemm_norm_kernel<64, __half><<<gb, 256, 0, stream>>>(hB, W3, out_norm, hA, N);
    agg_kernel<64, false, float><<<(N + 31) / 32, 256, 0, stream>>>(hA, row_ptr, col_idx,
                                                                    in_norm, b3, (float*)d_out, N);
}

// Round 6
// 388.022 us; speedup vs baseline: 1.8176x; 1.1938x over previous
//
#include <hip/hip_runtime.h>
#include <hip/hip_fp16.h>

// ---------------------------------------------------------------------------
// GCNEncoder: 3-layer GCN with symmetric norm and self-loops.
//   per layer: h = (x * out_norm) @ W ; agg = segsum(h[src], dst) + h (self)
//              out = agg * in_norm + b ; relu (layers 1,2)
// CSR build (by dst) -> aggregation is pure gather.
// R2: FAILED probe — device-atomic count has a ~20 G atomic/s write-through
//     floor. R3: LDS-atomic radix partition (zero device atomics).
// R4: inter-layer feature tables fp16 (agg gathers 256 B rows, L2-resident).
// R5: GEMMs moved to MFMA (v_mfma_f32_16x16x32_f16, fp16 in / fp32 acc),
//     W pre-transposed+converted to fp16 [N][K] once per call.
// ---------------------------------------------------------------------------

#define NFEAT 128
#define BBITS 8
#define BSZ 256                     // nodes per bucket
#define EPB 4096                    // edges per partition block (256 thr x 16)

union H8 { float4 f4; __half2 h2[4]; };   // 8 halves = 16 B

using half8v = __attribute__((ext_vector_type(8))) _Float16;
using f32x4  = __attribute__((ext_vector_type(4))) float;

// --- Pass 1: per-block LDS histograms over dst-buckets and src-buckets ---
__global__ __launch_bounds__(256) void hist_kernel(const int* __restrict__ src,
                                                   const int* __restrict__ dst,
                                                   int* __restrict__ histD,
                                                   int* __restrict__ histS,
                                                   int NB, int nblk, int E) {
    __shared__ int hd[512], hs[512];
    const int t = threadIdx.x, b = blockIdx.x;
    for (int u = t; u < 512; u += 256) { hd[u] = 0; hs[u] = 0; }
    __syncthreads();
    const int base4 = b * (EPB / 4);
    #pragma unroll
    for (int j = 0; j < 4; ++j) {
        int i4 = base4 + j * 256 + t;
        int e0 = i4 * 4;
        if (e0 + 3 < E) {
            int4 s = ((const int4*)src)[i4];
            int4 d = ((const int4*)dst)[i4];
            atomicAdd(&hs[s.x >> BBITS], 1); atomicAdd(&hs[s.y >> BBITS], 1);
            atomicAdd(&hs[s.z >> BBITS], 1); atomicAdd(&hs[s.w >> BBITS], 1);
            atomicAdd(&hd[d.x >> BBITS], 1); atomicAdd(&hd[d.y >> BBITS], 1);
            atomicAdd(&hd[d.z >> BBITS], 1); atomicAdd(&hd[d.w >> BBITS], 1);
        } else {
            for (int e = e0; e < E && e < e0 + 4; ++e) {
                atomicAdd(&hs[src[e] >> BBITS], 1);
                atomicAdd(&hd[dst[e] >> BBITS], 1);
            }
        }
    }
    __syncthreads();
    for (int u = t; u < NB; u += 256) {          // bucket-major layout [k*nblk + b]
        histD[u * nblk + b] = hd[u];
        histS[u * nblk + b] = hs[u];
    }
}

// --- multi-block exclusive scan (in-place capable) ---
__global__ __launch_bounds__(256) void scan1_kernel(const int* __restrict__ cnt,
                                                    int* __restrict__ excl,
                                                    int* __restrict__ blk_sum, int n) {
    const int tid = threadIdx.x, lane = tid & 63, wid = tid >> 6;  // 4 waves
    const int i = blockIdx.x * 256 + tid;
    int v = (i < n) ? cnt[i] : 0;
    int incl = v;
    #pragma unroll
    for (int off = 1; off < 64; off <<= 1) {
        int t = __shfl_up(incl, off, 64);
        if (lane >= off) incl += t;
    }
    __shared__ int ws[4];
    if (lane == 63) ws[wid] = incl;
    __syncthreads();
    int woff = 0;
    #pragma unroll
    for (int w = 0; w < 3; ++w) if (w < wid) woff += ws[w];
    if (i < n) excl[i] = woff + incl - v;
    if (tid == 0) blk_sum[blockIdx.x] = ws[0] + ws[1] + ws[2] + ws[3];
}

__global__ __launch_bounds__(1024) void scan2_kernel(int* __restrict__ blk,
                                                     int* __restrict__ grand_total, int nb) {
    const int tid = threadIdx.x, lane = tid & 63, wid = tid >> 6;  // 16 waves
    int v = (tid < nb) ? blk[tid] : 0;
    int incl = v;
    #pragma unroll
    for (int off = 1; off < 64; off <<= 1) {
        int t = __shfl_up(incl, off, 64);
        if (lane >= off) incl += t;
    }
    __shared__ int ws[16];
    if (lane == 63) ws[wid] = incl;
    __syncthreads();
    int woff = 0;
    #pragma unroll
    for (int w = 0; w < 15; ++w) if (w < wid) woff += ws[w];
    int excl = woff + incl - v;
    if (tid < nb) blk[tid] = excl;
    if (tid == nb - 1) *grand_total = excl + v;
}

__global__ void scan3_kernel(int* __restrict__ excl, const int* __restrict__ blk, int n) {
    int i = blockIdx.x * 256 + threadIdx.x;
    if (i < n) excl[i] += blk[blockIdx.x];
}

// --- Pass 2: scatter edges into bucket-partitioned arrays (LDS-atomic ranks) ---
__global__ __launch_bounds__(256) void scatter_kernel(const int* __restrict__ src,
                                                      const int* __restrict__ dst,
                                                      const int* __restrict__ offD,
                                                      const int* __restrict__ offS,
                                                      int* __restrict__ bsrc,
                                                      int* __restrict__ bdst,
                                                      int* __restrict__ ssrc,
                                                      int NB, int nblk, int E) {
    __shared__ int hd[512], hs[512], baseD[512], baseS[512];
    const int t = threadIdx.x, b = blockIdx.x;
    for (int u = t; u < 512; u += 256) { hd[u] = 0; hs[u] = 0; }
    for (int u = t; u < NB; u += 256) {
        baseD[u] = offD[u * nblk + b];
        baseS[u] = offS[u * nblk + b];
    }
    __syncthreads();
    const int base4 = b * (EPB / 4);
    #pragma unroll
    for (int j = 0; j < 4; ++j) {
        int i4 = base4 + j * 256 + t;
        int e0 = i4 * 4;
        if (e0 + 3 < E) {
            int4 s = ((const int4*)src)[i4];
            int4 d = ((const int4*)dst)[i4];
            int se[4] = {s.x, s.y, s.z, s.w};
            int de[4] = {d.x, d.y, d.z, d.w};
            #pragma unroll
            for (int q = 0; q < 4; ++q) {
                int kd = de[q] >> BBITS;
                int pos = baseD[kd] + atomicAdd(&hd[kd], 1);
                bdst[pos] = de[q];
                bsrc[pos] = se[q];
                int ks = se[q] >> BBITS;
                int posS = baseS[ks] + atomicAdd(&hs[ks], 1);
                ssrc[posS] = se[q];
            }
        } else {
            for (int e = e0; e < E && e < e0 + 4; ++e) {
                int sv = src[e], dv = dst[e];
                int kd = dv >> BBITS;
                int pos = baseD[kd] + atomicAdd(&hd[kd], 1);
                bdst[pos] = dv;
                bsrc[pos] = sv;
                int ks = sv >> BBITS;
                int posS = baseS[ks] + atomicAdd(&hs[ks], 1);
                ssrc[posS] = sv;
            }
        }
    }
}

// --- Pass 3: per-bucket CSR finalize + degrees + norms (all LDS) ---
__global__ __launch_bounds__(256) void bucket_kernel(const int* __restrict__ bsrc,
                                                     const int* __restrict__ bdst,
                                                     const int* __restrict__ ssrc,
                                                     const int* __restrict__ offD,
                                                     const int* __restrict__ offS,
                                                     int* __restrict__ row_ptr,
                                                     int* __restrict__ col_idx,
                                                     float* __restrict__ in_norm,
                                                     float* __restrict__ out_norm,
                                                     int N, int NB, int nblk, int E) {
    __shared__ int cnt[BSZ], scnt[BSZ], start[BSZ], off[BSZ];
    __shared__ int ws[4];
    const int k = blockIdx.x, t = threadIdx.x;
    const int node0 = k << BBITS;
    cnt[t] = 0; scnt[t] = 0; off[t] = 0;
    __syncthreads();
    const int bB = offD[k * nblk], bE = (k + 1 < NB) ? offD[(k + 1) * nblk] : E;
    const int sB = offS[k * nblk], sE = (k + 1 < NB) ? offS[(k + 1) * nblk] : E;
    for (int i = bB + t; i < bE; i += 256) atomicAdd(&cnt[bdst[i] - node0], 1);
    for (int i = sB + t; i < sE; i += 256) atomicAdd(&scnt[ssrc[i] - node0], 1);
    __syncthreads();
    const int lane = t & 63, wid = t >> 6;
    int v = cnt[t];
    int incl = v;
    #pragma unroll
    for (int o = 1; o < 64; o <<= 1) {
        int x = __shfl_up(incl, o, 64);
        if (lane >= o) incl += x;
    }
    if (lane == 63) ws[wid] = incl;
    __syncthreads();
    int woff = 0;
    #pragma unroll
    for (int w = 0; w < 3; ++w) if (w < wid) woff += ws[w];
    start[t] = woff + incl - v;
    {
        int node = node0 + t;
        if (node < N) {
            row_ptr[node] = bB + start[t];
            in_norm[node]  = rsqrtf((float)(v + 1));          // +1 self-loop
            out_norm[node] = rsqrtf((float)(scnt[t] + 1));
        }
    }
    if (k == 0 && t == 0) row_ptr[N] = E;
    __syncthreads();
    for (int i = bB + t; i < bE; i += 256) {
        int local = bdst[i] - node0;
        int r = atomicAdd(&off[local], 1);
        col_idx[bB + start[local] + r] = bsrc[i];
    }
}

// --- W [K][Ncols] fp32 -> Wt [Ncols][K=128] fp16 (once per call, tiny) ---
__global__ void wt_kernel(const float* __restrict__ W, __half* __restrict__ Wt, int Ncols) {
    int n = blockIdx.x;       // 0..Ncols-1
    int k = threadIdx.x;      // 0..127
    Wt[n * 128 + k] = __float2half(W[k * Ncols + n]);
}

// --- MFMA GEMM: h[64 rows x BN] = fp16(x * out_norm) @ W, K = 128 ---
// A, Wt staged in LDS (136-half rows: 272 B stride, 4-bank rotation).
// 4 waves x 16 rows; fragments: A[m=lane&15][k=quad*8+j], B=Wt row n=lane&15.
// C/D: col=lane&15, row=quad*4+reg  (guide §3, m89-verified).
template <int BN, typename XT>
__global__ __launch_bounds__(256) void mfma_gemm_kernel(const XT* __restrict__ x,
                                                        const __half* __restrict__ Wt,
                                                        const float* __restrict__ out_norm,
                                                        __half* __restrict__ h, int n_rows) {
    constexpr int BM = 64;
    constexpr int NT = BN / 16;          // 8 (BN=128) or 4 (BN=64)
    __shared__ __half As[BM][136];
    __shared__ __half Bs[BN][136];
    const int tid  = threadIdx.x;
    const int row0 = blockIdx.x * BM;

    // --- stage A: 64 rows x 128 halves, scaled by out_norm, fp16 ---
    {
        int r  = tid >> 2;                 // 0..63
        int c0 = (tid & 3) * 32;           // 0,32,64,96
        int grow = row0 + r;
        if (grow < n_rows) {
            float norm = out_norm[grow];
            if constexpr (sizeof(XT) == 4) {
                const float* xp = (const float*)x + (size_t)grow * NFEAT + c0;
                #pragma unroll
                for (int j = 0; j < 4; ++j) {
                    float4 p0 = *(const float4*)(xp + j * 8);
                    float4 p1 = *(const float4*)(xp + j * 8 + 4);
                    H8 u;
                    u.h2[0] = __floats2half2_rn(p0.x * norm, p0.y * norm);
                    u.h2[1] = __floats2half2_rn(p0.z * norm, p0.w * norm);
                    u.h2[2] = __floats2half2_rn(p1.x * norm, p1.y * norm);
                    u.h2[3] = __floats2half2_rn(p1.z * norm, p1.w * norm);
                    *(float4*)&As[r][c0 + j * 8] = u.f4;
                }
            } else {
                const __half* xp = (const __half*)x + (size_t)grow * NFEAT + c0;
                #pragma unroll
                for (int j = 0; j < 4; ++j) {
                    H8 u; u.f4 = *(const float4*)(xp + j * 8);
                    #pragma unroll
                    for (int q = 0; q < 4; ++q) {
                        float2 p = __half22float2(u.h2[q]);
                        u.h2[q] = __floats2half2_rn(p.x * norm, p.y * norm);
                    }
                    *(float4*)&As[r][c0 + j * 8] = u.f4;
                }
            }
        } else {
            H8 z; z.f4 = make_float4(0.f, 0.f, 0.f, 0.f);
            #pragma unroll
            for (int j = 0; j < 4; ++j) *(float4*)&As[r][c0 + j * 8] = z.f4;
        }
    }
    // --- stage Wt: BN rows x 128 halves ---
    {
        constexpr int TPR = 256 / BN;              // threads per row: 2 or 4
        constexpr int CH  = 128 / TPR;             // halves per thread: 64 or 32
        int wr = tid / TPR;
        int wc = (tid % TPR) * CH;
        const __half* wp = Wt + wr * 128 + wc;
        #pragma unroll
        for (int j = 0; j < CH / 8; ++j)
            *(float4*)&Bs[wr][wc + j * 8] = *(const float4*)(wp + j * 8);
    }
    __syncthreads();

    const int lane = tid & 63, wid = tid >> 6;
    const int lr = lane & 15, quad = lane >> 4;
    const int koff = quad * 8;
    f32x4 acc[NT];
    #pragma unroll
    for (int t = 0; t < NT; ++t) acc[t] = (f32x4){0.f, 0.f, 0.f, 0.f};

    #pragma unroll
    for (int ks = 0; ks < 4; ++ks) {
        half8v a = *(const half8v*)&As[wid * 16 + lr][ks * 32 + koff];
        #pragma unroll
        for (int nt = 0; nt < NT; ++nt) {
            half8v b = *(const half8v*)&Bs[nt * 16 + lr][ks * 32 + koff];
            acc[nt] = __builtin_amdgcn_mfma_f32_16x16x32_f16(a, b, acc[nt], 0, 0, 0);
        }
    }

    #pragma unroll
    for (int nt = 0; nt < NT; ++nt) {
        #pragma unroll
        for (int r = 0; r < 4; ++r) {
            int row = row0 + wid * 16 + quad * 4 + r;
            if (row < n_rows)
                h[(size_t)row * BN + nt * 16 + lr] = __float2half(acc[nt][r]);
        }
    }
}

// Gather aggregation + epilogue: out = (sum_in h[src] + h[node]) * in_norm + b [, relu]
template <int DOUT, bool RELU, typename OutT>
__global__ __launch_bounds__(256) void agg_kernel(const __half* __restrict__ h,
                                                  const int* __restrict__ row_ptr,
                                                  const int* __restrict__ col_idx,
                                                  const float* __restrict__ in_norm,
                                                  const float* __restrict__ bias,
                                                  OutT* __restrict__ out, int n) {
    constexpr int TPN = DOUT / 8;      // threads per node (8 halves = 16 B each)
    constexpr int NPB = 256 / TPN;     // nodes per block
    const int tid  = threadIdx.x;
    const int sub  = tid / TPN;
    const int c    = (tid % TPN) * 8;
    const int node = blockIdx.x * NPB + sub;
    if (node >= n) return;

    float acc[8];
    {
        H8 u; u.f4 = *(const float4*)(h + (size_t)node * DOUT + c);  // self-loop
        #pragma unroll
        for (int q = 0; q < 4; ++q) {
            float2 p = __half22float2(u.h2[q]);
            acc[q * 2] = p.x; acc[q * 2 + 1] = p.y;
        }
    }
    int e  = row_ptr[node];
    int e1 = row_ptr[node + 1];
    for (; e + 3 < e1; e += 4) {
        int s0 = col_idx[e], s1 = col_idx[e + 1], s2 = col_idx[e + 2], s3 = col_idx[e + 3];
        H8 u0, u1, u2, u3;
        u0.f4 = *(const float4*)(h + (size_t)s0 * DOUT + c);
        u1.f4 = *(const float4*)(h + (size_t)s1 * DOUT + c);
        u2.f4 = *(const float4*)(h + (size_t)s2 * DOUT + c);
        u3.f4 = *(const float4*)(h + (size_t)s3 * DOUT + c);
        #pragma unroll
        for (int q = 0; q < 4; ++q) {
            float2 p0 = __half22float2(u0.h2[q]);
            float2 p1 = __half22float2(u1.h2[q]);
            float2 p2 = __half22float2(u2.h2[q]);
            float2 p3 = __half22float2(u3.h2[q]);
            acc[q * 2]     += (p0.x + p1.x) + (p2.x + p3.x);
            acc[q * 2 + 1] += (p0.y + p1.y) + (p2.y + p3.y);
        }
    }
    for (; e < e1; ++e) {
        int s0 = col_idx[e];
        H8 u0; u0.f4 = *(const float4*)(h + (size_t)s0 * DOUT + c);
        #pragma unroll
        for (int q = 0; q < 4; ++q) {
            float2 p0 = __half22float2(u0.h2[q]);
            acc[q * 2] += p0.x; acc[q * 2 + 1] += p0.y;
        }
    }
    float inn = in_norm[node];
    float r[8];
    #pragma unroll
    for (int q = 0; q < 8; ++q) {
        r[q] = acc[q] * inn + bias[c + q];
        if (RELU) r[q] = fmaxf(r[q], 0.0f);
    }
    if constexpr (sizeof(OutT) == 2) {
        H8 o;
        #pragma unroll
        for (int q = 0; q < 4; ++q) o.h2[q] = __floats2half2_rn(r[q * 2], r[q * 2 + 1]);
        *(float4*)((__half*)out + (size_t)node * DOUT + c) = o.f4;
    } else {
        float4 o0, o1;
        o0.x=r[0]; o0.y=r[1]; o0.z=r[2]; o0.w=r[3];
        o1.x=r[4]; o1.y=r[5]; o1.z=r[6]; o1.w=r[7];
        *(float4*)((float*)out + (size_t)node * DOUT + c)     = o0;
        *(float4*)((float*)out + (size_t)node * DOUT + c + 4) = o1;
    }
}

extern "C" void kernel_launch(void* const* d_in, const int* in_sizes, int n_in,
                              void* d_out, int out_size, void* d_ws, size_t ws_size,
                              hipStream_t stream) {
    const float* feat = (const float*)d_in[0];
    const int*   src  = (const int*)d_in[1];
    const int*   dst  = (const int*)d_in[2];
    const float* W1   = (const float*)d_in[3];
    const float* b1   = (const float*)d_in[4];
    const float* W2   = (const float*)d_in[5];
    const float* b2   = (const float*)d_in[6];
    const float* W3   = (const float*)d_in[7];
    const float* b3   = (const float*)d_in[8];

    const int N = in_sizes[0] / NFEAT;   // 100000
    const int E = in_sizes[1];           // 1600000

    const int NB   = (N + BSZ - 1) / BSZ;        // 391 buckets
    const int nblk = (E + EPB - 1) / EPB;        // 391 partition blocks
    const int nh   = NB * nblk;                  // hist elements (152,881)
    const int nsb  = (nh + 255) / 256;           // scan blocks (598 <= 1024)

    char* ws = (char*)d_ws;
    auto alloc = [&](size_t bytes) {
        char* p = ws;
        ws += (bytes + 255) & ~(size_t)255;
        return p;
    };
    float* out_norm = (float*)alloc((size_t)N * 4);
    float* in_norm  = (float*)alloc((size_t)N * 4);
    int*   row_ptr  = (int*)alloc((size_t)(N + 1) * 4);
    int*   histD    = (int*)alloc((size_t)nh * 4);
    int*   histS    = (int*)alloc((size_t)nh * 4);
    int*   blk_sum  = (int*)alloc((size_t)1024 * 4);
    int*   scratch  = (int*)alloc((size_t)16 * 4);
    __half* Wt1     = (__half*)alloc((size_t)128 * 128 * 2);
    __half* Wt2     = (__half*)alloc((size_t)128 * 128 * 2);
    __half* Wt3     = (__half*)alloc((size_t)64 * 128 * 2);
    int*   col_idx  = (int*)alloc((size_t)E * 4);
    // hA region also hosts the 3 partition arrays (3*E*4 = 19.2 MB <= 25.6 MB)
    __half* hA      = (__half*)alloc((size_t)N * NFEAT * 2);
    __half* hB      = (__half*)alloc((size_t)N * NFEAT * 2);
    int*   bdst     = (int*)hA;
    int*   bsrc     = (int*)hA + E;
    int*   ssrc     = (int*)hA + 2 * (size_t)E;

    // --- weight transpose/convert (independent, tiny) ---
    wt_kernel<<<128, 128, 0, stream>>>(W1, Wt1, 128);
    wt_kernel<<<128, 128, 0, stream>>>(W2, Wt2, 128);
    wt_kernel<<<64, 128, 0, stream>>>(W3, Wt3, 64);

    // --- CSR build: hist -> scan(D) -> scan(S) -> scatter -> bucket ---
    hist_kernel<<<nblk, 256, 0, stream>>>(src, dst, histD, histS, NB, nblk, E);
    scan1_kernel<<<nsb, 256, 0, stream>>>(histD, histD, blk_sum, nh);
    scan2_kernel<<<1, 1024, 0, stream>>>(blk_sum, scratch, nsb);
    scan3_kernel<<<nsb, 256, 0, stream>>>(histD, blk_sum, nh);
    scan1_kernel<<<nsb, 256, 0, stream>>>(histS, histS, blk_sum, nh);
    scan2_kernel<<<1, 1024, 0, stream>>>(blk_sum, scratch, nsb);
    scan3_kernel<<<nsb, 256, 0, stream>>>(histS, blk_sum, nh);
    scatter_kernel<<<nblk, 256, 0, stream>>>(src, dst, histD, histS, bsrc, bdst, ssrc, NB, nblk, E);
    bucket_kernel<<<NB, 256, 0, stream>>>(bsrc, bdst, ssrc, histD, histS, row_ptr, col_idx,
                                          in_norm, out_norm, N, NB, nblk, E);

    const int gb = (N + 63) / 64;
    // layer 1 (x fp32 -> h fp16)
    mfma_gemm_kernel<128, float><<<gb, 256, 0, stream>>>(feat, Wt1, out_norm, hA, N);
    agg_kernel<128, true, __half><<<(N + 15) / 16, 256, 0, stream>>>(hA, row_ptr, col_idx,
                                                                     in_norm, b1, hB, N);
    // layer 2 (fp16 -> fp16)
    mfma_gemm_kernel<128, __half><<<gb, 256, 0, stream>>>(hB, Wt2, out_norm, hA, N);
    agg_kernel<128, true, __half><<<(N + 15) / 16, 256, 0, stream>>>(hA, row_ptr, col_idx,
                                                                     in_norm, b2, hB, N);
    // layer 3 (fp16 -> fp32 d_out, no relu)
    mfma_gemm_kernel<64, __half><<<gb, 256, 0, stream>>>(hB, Wt3, out_norm, hA, N);
    agg_kernel<64, false, float><<<(N + 31) / 32, 256, 0, stream>>>(hA, row_ptr, col_idx,
                                                                    in_norm, b3, (float*)d_out, N);
}

// Round 7
// 357.163 us; speedup vs baseline: 1.9747x; 1.0864x over previous
//
#include <hip/hip_runtime.h>
#include <hip/hip_fp16.h>

// ---------------------------------------------------------------------------
// GCNEncoder: 3-layer GCN with symmetric norm and self-loops.
//   per layer: h = (x * out_norm) @ W ; agg = segsum(h[src], dst) + h (self)
//              out = agg * in_norm + b ; relu (layers 1,2)
// CSR build (by dst) -> aggregation is pure gather.
// R2: FAILED probe — device-atomic count has a ~20 G atomic/s write-through
//     floor. R3: LDS-atomic radix partition (zero device atomics).
// R4: inter-layer feature tables fp16 (agg gathers 256 B rows, L2-resident).
// R5: GEMMs on MFMA (v_mfma_f32_16x16x32_f16), W pre-transposed fp16.
// R6: CSR-build slimming — packed scatter payloads (uint: dst_local<<24|src;
//     uint8 src_local), single concatenated hist scan (6 launches -> 3),
//     merged wt kernel. Scatter/bucket traffic 19.2 MB -> 8 MB each way.
// ---------------------------------------------------------------------------

#define NFEAT 128
#define BBITS 8
#define BSZ 256                     // nodes per bucket
#define EPB 4096                    // edges per partition block (256 thr x 16)

union H8 { float4 f4; __half2 h2[4]; };   // 8 halves = 16 B

using half8v = __attribute__((ext_vector_type(8))) _Float16;
using f32x4  = __attribute__((ext_vector_type(4))) float;

// --- Pass 1: per-block LDS histograms; hist2 = [D part | S part], bucket-major ---
__global__ __launch_bounds__(256) void hist_kernel(const int* __restrict__ src,
                                                   const int* __restrict__ dst,
                                                   int* __restrict__ hist2,
                                                   int NB, int nblk, int nh, int E) {
    __shared__ int hd[512], hs[512];
    const int t = threadIdx.x, b = blockIdx.x;
    for (int u = t; u < 512; u += 256) { hd[u] = 0; hs[u] = 0; }
    __syncthreads();
    const int base4 = b * (EPB / 4);
    #pragma unroll
    for (int j = 0; j < 4; ++j) {
        int i4 = base4 + j * 256 + t;
        int e0 = i4 * 4;
        if (e0 + 3 < E) {
            int4 s = ((const int4*)src)[i4];
            int4 d = ((const int4*)dst)[i4];
            atomicAdd(&hs[s.x >> BBITS], 1); atomicAdd(&hs[s.y >> BBITS], 1);
            atomicAdd(&hs[s.z >> BBITS], 1); atomicAdd(&hs[s.w >> BBITS], 1);
            atomicAdd(&hd[d.x >> BBITS], 1); atomicAdd(&hd[d.y >> BBITS], 1);
            atomicAdd(&hd[d.z >> BBITS], 1); atomicAdd(&hd[d.w >> BBITS], 1);
        } else {
            for (int e = e0; e < E && e < e0 + 4; ++e) {
                atomicAdd(&hs[src[e] >> BBITS], 1);
                atomicAdd(&hd[dst[e] >> BBITS], 1);
            }
        }
    }
    __syncthreads();
    for (int u = t; u < NB; u += 256) {
        hist2[u * nblk + b]      = hd[u];
        hist2[nh + u * nblk + b] = hs[u];
    }
}

// --- 3-kernel exclusive scan, 2 elements/thread (512/block), in-place ---
__global__ __launch_bounds__(256) void scan1_kernel(int* __restrict__ data,
                                                    int* __restrict__ blk_sum, int n) {
    const int tid = threadIdx.x, lane = tid & 63, wid = tid >> 6;  // 4 waves
    const int i2 = blockIdx.x * 256 + tid;
    int a = 0, b = 0;
    if (2 * i2 + 1 < n)      { int2 v = ((const int2*)data)[i2]; a = v.x; b = v.y; }
    else if (2 * i2 < n)     { a = data[2 * i2]; }
    int s = a + b;
    int incl = s;
    #pragma unroll
    for (int off = 1; off < 64; off <<= 1) {
        int t2 = __shfl_up(incl, off, 64);
        if (lane >= off) incl += t2;
    }
    __shared__ int ws[4];
    if (lane == 63) ws[wid] = incl;
    __syncthreads();
    int woff = 0;
    #pragma unroll
    for (int w = 0; w < 3; ++w) if (w < wid) woff += ws[w];
    int pref = woff + incl - s;              // exclusive prefix of this thread's pair
    if (2 * i2 < n)     data[2 * i2]     = pref;
    if (2 * i2 + 1 < n) data[2 * i2 + 1] = pref + a;
    if (tid == 0) blk_sum[blockIdx.x] = ws[0] + ws[1] + ws[2] + ws[3];
}

__global__ __launch_bounds__(1024) void scan2_kernel(int* __restrict__ blk, int nb) {
    const int tid = threadIdx.x, lane = tid & 63, wid = tid >> 6;  // 16 waves
    int v = (tid < nb) ? blk[tid] : 0;
    int incl = v;
    #pragma unroll
    for (int off = 1; off < 64; off <<= 1) {
        int t = __shfl_up(incl, off, 64);
        if (lane >= off) incl += t;
    }
    __shared__ int ws[16];
    if (lane == 63) ws[wid] = incl;
    __syncthreads();
    int woff = 0;
    #pragma unroll
    for (int w = 0; w < 15; ++w) if (w < wid) woff += ws[w];
    if (tid < nb) blk[tid] = woff + incl - v;
}

__global__ __launch_bounds__(256) void scan3_kernel(int* __restrict__ data,
                                                    const int* __restrict__ blk, int n) {
    const int i2 = blockIdx.x * 256 + threadIdx.x;
    int add = blk[blockIdx.x];
    if (2 * i2 < n)     data[2 * i2]     += add;
    if (2 * i2 + 1 < n) data[2 * i2 + 1] += add;
}

// --- Pass 2: scatter edges; packed payloads (uint dst_local<<24|src; uint8 src_local) ---
__global__ __launch_bounds__(256) void scatter_kernel(const int* __restrict__ src,
                                                      const int* __restrict__ dst,
                                                      const int* __restrict__ hist2,
                                                      unsigned int* __restrict__ dstP,
                                                      unsigned char* __restrict__ srcB,
                                                      int NB, int nblk, int nh, int E) {
    __shared__ int hd[512], hs[512], baseD[512], baseS[512];
    const int t = threadIdx.x, b = blockIdx.x;
    for (int u = t; u < 512; u += 256) { hd[u] = 0; hs[u] = 0; }
    for (int u = t; u < NB; u += 256) {
        baseD[u] = hist2[u * nblk + b];
        baseS[u] = hist2[nh + u * nblk + b] - E;   // S region offsets were scanned after D (sum D = E)
    }
    __syncthreads();
    const int base4 = b * (EPB / 4);
    #pragma unroll
    for (int j = 0; j < 4; ++j) {
        int i4 = base4 + j * 256 + t;
        int e0 = i4 * 4;
        if (e0 + 3 < E) {
            int4 s = ((const int4*)src)[i4];
            int4 d = ((const int4*)dst)[i4];
            int se[4] = {s.x, s.y, s.z, s.w};
            int de[4] = {d.x, d.y, d.z, d.w};
            #pragma unroll
            for (int q = 0; q < 4; ++q) {
                int kd = de[q] >> BBITS;
                int pos = baseD[kd] + atomicAdd(&hd[kd], 1);
                dstP[pos] = ((unsigned int)(de[q] & (BSZ - 1)) << 24) | (unsigned int)se[q];
                int ks = se[q] >> BBITS;
                int posS = baseS[ks] + atomicAdd(&hs[ks], 1);
                srcB[posS] = (unsigned char)(se[q] & (BSZ - 1));
            }
        } else {
            for (int e = e0; e < E && e < e0 + 4; ++e) {
                int sv = src[e], dv = dst[e];
                int kd = dv >> BBITS;
                int pos = baseD[kd] + atomicAdd(&hd[kd], 1);
                dstP[pos] = ((unsigned int)(dv & (BSZ - 1)) << 24) | (unsigned int)sv;
                int ks = sv >> BBITS;
                int posS = baseS[ks] + atomicAdd(&hs[ks], 1);
                srcB[posS] = (unsigned char)(sv & (BSZ - 1));
            }
        }
    }
}

// --- Pass 3: per-bucket CSR finalize + degrees + norms (all LDS) ---
__global__ __launch_bounds__(256) void bucket_kernel(const unsigned int* __restrict__ dstP,
                                                     const unsigned char* __restrict__ srcB,
                                                     const int* __restrict__ hist2,
                                                     int* __restrict__ row_ptr,
                                                     int* __restrict__ col_idx,
                                                     float* __restrict__ in_norm,
                                                     float* __restrict__ out_norm,
                                                     int N, int NB, int nblk, int nh, int E) {
    __shared__ int cnt[BSZ], scnt[BSZ], start[BSZ], off[BSZ];
    __shared__ int ws[4];
    const int k = blockIdx.x, t = threadIdx.x;
    const int node0 = k << BBITS;
    cnt[t] = 0; scnt[t] = 0; off[t] = 0;
    __syncthreads();
    const int bB = hist2[k * nblk];
    const int bE = (k + 1 < NB) ? hist2[(k + 1) * nblk] : E;
    const int sB = hist2[nh + k * nblk] - E;
    const int sE = ((k + 1 < NB) ? hist2[nh + (k + 1) * nblk] : 2 * E) - E;
    for (int i = bB + t; i < bE; i += 256) atomicAdd(&cnt[dstP[i] >> 24], 1);
    for (int i = sB + t; i < sE; i += 256) atomicAdd(&scnt[srcB[i]], 1);
    __syncthreads();
    const int lane = t & 63, wid = t >> 6;
    int v = cnt[t];
    int incl = v;
    #pragma unroll
    for (int o = 1; o < 64; o <<= 1) {
        int x = __shfl_up(incl, o, 64);
        if (lane >= o) incl += x;
    }
    if (lane == 63) ws[wid] = incl;
    __syncthreads();
    int woff = 0;
    #pragma unroll
    for (int w = 0; w < 3; ++w) if (w < wid) woff += ws[w];
    start[t] = woff + incl - v;
    {
        int node = node0 + t;
        if (node < N) {
            row_ptr[node] = bB + start[t];
            in_norm[node]  = rsqrtf((float)(v + 1));          // +1 self-loop
            out_norm[node] = rsqrtf((float)(scnt[t] + 1));
        }
    }
    if (k == 0 && t == 0) row_ptr[N] = E;
    __syncthreads();
    for (int i = bB + t; i < bE; i += 256) {
        unsigned int pv = dstP[i];
        int local = pv >> 24;
        int r = atomicAdd(&off[local], 1);
        col_idx[bB + start[local] + r] = (int)(pv & 0xFFFFFFu);
    }
}

// --- all three W [K][Ncols] fp32 -> Wt [Ncols][K=128] fp16 in one launch ---
__global__ void wt_all_kernel(const float* __restrict__ W1, const float* __restrict__ W2,
                              const float* __restrict__ W3, __half* __restrict__ Wt1,
                              __half* __restrict__ Wt2, __half* __restrict__ Wt3) {
    int b = blockIdx.x, k = threadIdx.x;
    if (b < 128)      Wt1[b * 128 + k] = __float2half(W1[k * 128 + b]);
    else if (b < 256) { int n = b - 128; Wt2[n * 128 + k] = __float2half(W2[k * 128 + n]); }
    else              { int n = b - 256; Wt3[n * 128 + k] = __float2half(W3[k * 64 + n]); }
}

// --- MFMA GEMM: h[64 rows x BN] = fp16(x * out_norm) @ W, K = 128 ---
template <int BN, typename XT>
__global__ __launch_bounds__(256) void mfma_gemm_kernel(const XT* __restrict__ x,
                                                        const __half* __restrict__ Wt,
                                                        const float* __restrict__ out_norm,
                                                        __half* __restrict__ h, int n_rows) {
    constexpr int BM = 64;
    constexpr int NT = BN / 16;          // 8 (BN=128) or 4 (BN=64)
    __shared__ __half As[BM][136];
    __shared__ __half Bs[BN][136];
    const int tid  = threadIdx.x;
    const int row0 = blockIdx.x * BM;

    {
        int r  = tid >> 2;                 // 0..63
        int c0 = (tid & 3) * 32;           // 0,32,64,96
        int grow = row0 + r;
        if (grow < n_rows) {
            float norm = out_norm[grow];
            if constexpr (sizeof(XT) == 4) {
                const float* xp = (const float*)x + (size_t)grow * NFEAT + c0;
                #pragma unroll
                for (int j = 0; j < 4; ++j) {
                    float4 p0 = *(const float4*)(xp + j * 8);
                    float4 p1 = *(const float4*)(xp + j * 8 + 4);
                    H8 u;
                    u.h2[0] = __floats2half2_rn(p0.x * norm, p0.y * norm);
                    u.h2[1] = __floats2half2_rn(p0.z * norm, p0.w * norm);
                    u.h2[2] = __floats2half2_rn(p1.x * norm, p1.y * norm);
                    u.h2[3] = __floats2half2_rn(p1.z * norm, p1.w * norm);
                    *(float4*)&As[r][c0 + j * 8] = u.f4;
                }
            } else {
                const __half* xp = (const __half*)x + (size_t)grow * NFEAT + c0;
                #pragma unroll
                for (int j = 0; j < 4; ++j) {
                    H8 u; u.f4 = *(const float4*)(xp + j * 8);
                    #pragma unroll
                    for (int q = 0; q < 4; ++q) {
                        float2 p = __half22float2(u.h2[q]);
                        u.h2[q] = __floats2half2_rn(p.x * norm, p.y * norm);
                    }
                    *(float4*)&As[r][c0 + j * 8] = u.f4;
                }
            }
        } else {
            H8 z; z.f4 = make_float4(0.f, 0.f, 0.f, 0.f);
            #pragma unroll
            for (int j = 0; j < 4; ++j) *(float4*)&As[r][c0 + j * 8] = z.f4;
        }
    }
    {
        constexpr int TPR = 256 / BN;              // threads per row: 2 or 4
        constexpr int CH  = 128 / TPR;             // halves per thread: 64 or 32
        int wr = tid / TPR;
        int wc = (tid % TPR) * CH;
        const __half* wp = Wt + wr * 128 + wc;
        #pragma unroll
        for (int j = 0; j < CH / 8; ++j)
            *(float4*)&Bs[wr][wc + j * 8] = *(const float4*)(wp + j * 8);
    }
    __syncthreads();

    const int lane = tid & 63, wid = tid >> 6;
    const int lr = lane & 15, quad = lane >> 4;
    const int koff = quad * 8;
    f32x4 acc[NT];
    #pragma unroll
    for (int t = 0; t < NT; ++t) acc[t] = (f32x4){0.f, 0.f, 0.f, 0.f};

    #pragma unroll
    for (int ks = 0; ks < 4; ++ks) {
        half8v a = *(const half8v*)&As[wid * 16 + lr][ks * 32 + koff];
        #pragma unroll
        for (int nt = 0; nt < NT; ++nt) {
            half8v b = *(const half8v*)&Bs[nt * 16 + lr][ks * 32 + koff];
            acc[nt] = __builtin_amdgcn_mfma_f32_16x16x32_f16(a, b, acc[nt], 0, 0, 0);
        }
    }

    #pragma unroll
    for (int nt = 0; nt < NT; ++nt) {
        #pragma unroll
        for (int r = 0; r < 4; ++r) {
            int row = row0 + wid * 16 + quad * 4 + r;
            if (row < n_rows)
                h[(size_t)row * BN + nt * 16 + lr] = __float2half(acc[nt][r]);
        }
    }
}

// Gather aggregation + epilogue: out = (sum_in h[src] + h[node]) * in_norm + b [, relu]
template <int DOUT, bool RELU, typename OutT>
__global__ __launch_bounds__(256) void agg_kernel(const __half* __restrict__ h,
                                                  const int* __restrict__ row_ptr,
                                                  const int* __restrict__ col_idx,
                                                  const float* __restrict__ in_norm,
                                                  const float* __restrict__ bias,
                                                  OutT* __restrict__ out, int n) {
    constexpr int TPN = DOUT / 8;      // threads per node (8 halves = 16 B each)
    constexpr int NPB = 256 / TPN;     // nodes per block
    const int tid  = threadIdx.x;
    const int sub  = tid / TPN;
    const int c    = (tid % TPN) * 8;
    const int node = blockIdx.x * NPB + sub;
    if (node >= n) return;

    float acc[8];
    {
        H8 u; u.f4 = *(const float4*)(h + (size_t)node * DOUT + c);  // self-loop
        #pragma unroll
        for (int q = 0; q < 4; ++q) {
            float2 p = __half22float2(u.h2[q]);
            acc[q * 2] = p.x; acc[q * 2 + 1] = p.y;
        }
    }
    int e  = row_ptr[node];
    int e1 = row_ptr[node + 1];
    for (; e + 3 < e1; e += 4) {
        int s0 = col_idx[e], s1 = col_idx[e + 1], s2 = col_idx[e + 2], s3 = col_idx[e + 3];
        H8 u0, u1, u2, u3;
        u0.f4 = *(const float4*)(h + (size_t)s0 * DOUT + c);
        u1.f4 = *(const float4*)(h + (size_t)s1 * DOUT + c);
        u2.f4 = *(const float4*)(h + (size_t)s2 * DOUT + c);
        u3.f4 = *(const float4*)(h + (size_t)s3 * DOUT + c);
        #pragma unroll
        for (int q = 0; q < 4; ++q) {
            float2 p0 = __half22float2(u0.h2[q]);
            float2 p1 = __half22float2(u1.h2[q]);
            float2 p2 = __half22float2(u2.h2[q]);
            float2 p3 = __half22float2(u3.h2[q]);
            acc[q * 2]     += (p0.x + p1.x) + (p2.x + p3.x);
            acc[q * 2 + 1] += (p0.y + p1.y) + (p2.y + p3.y);
        }
    }
    for (; e < e1; ++e) {
        int s0 = col_idx[e];
        H8 u0; u0.f4 = *(const float4*)(h + (size_t)s0 * DOUT + c);
        #pragma unroll
        for (int q = 0; q < 4; ++q) {
            float2 p0 = __half22float2(u0.h2[q]);
            acc[q * 2] += p0.x; acc[q * 2 + 1] += p0.y;
        }
    }
    float inn = in_norm[node];
    float r[8];
    #pragma unroll
    for (int q = 0; q < 8; ++q) {
        r[q] = acc[q] * inn + bias[c + q];
        if (RELU) r[q] = fmaxf(r[q], 0.0f);
    }
    if constexpr (sizeof(OutT) == 2) {
        H8 o;
        #pragma unroll
        for (int q = 0; q < 4; ++q) o.h2[q] = __floats2half2_rn(r[q * 2], r[q * 2 + 1]);
        *(float4*)((__half*)out + (size_t)node * DOUT + c) = o.f4;
    } else {
        float4 o0, o1;
        o0.x=r[0]; o0.y=r[1]; o0.z=r[2]; o0.w=r[3];
        o1.x=r[4]; o1.y=r[5]; o1.z=r[6]; o1.w=r[7];
        *(float4*)((float*)out + (size_t)node * DOUT + c)     = o0;
        *(float4*)((float*)out + (size_t)node * DOUT + c + 4) = o1;
    }
}

extern "C" void kernel_launch(void* const* d_in, const int* in_sizes, int n_in,
                              void* d_out, int out_size, void* d_ws, size_t ws_size,
                              hipStream_t stream) {
    const float* feat = (const float*)d_in[0];
    const int*   src  = (const int*)d_in[1];
    const int*   dst  = (const int*)d_in[2];
    const float* W1   = (const float*)d_in[3];
    const float* b1   = (const float*)d_in[4];
    const float* W2   = (const float*)d_in[5];
    const float* b2   = (const float*)d_in[6];
    const float* W3   = (const float*)d_in[7];
    const float* b3   = (const float*)d_in[8];

    const int N = in_sizes[0] / NFEAT;   // 100000
    const int E = in_sizes[1];           // 1600000

    const int NB   = (N + BSZ - 1) / BSZ;        // 391 buckets
    const int nblk = (E + EPB - 1) / EPB;        // 391 partition blocks
    const int nh   = NB * nblk;                  // hist elements per side (152,881)
    const int n2   = 2 * nh;                     // concatenated [D|S]
    const int nsb  = (n2 + 511) / 512;           // scan blocks (598 <= 1024)

    char* ws = (char*)d_ws;
    auto alloc = [&](size_t bytes) {
        char* p = ws;
        ws += (bytes + 255) & ~(size_t)255;
        return p;
    };
    float* out_norm = (float*)alloc((size_t)N * 4);
    float* in_norm  = (float*)alloc((size_t)N * 4);
    int*   row_ptr  = (int*)alloc((size_t)(N + 1) * 4);
    int*   hist2    = (int*)alloc((size_t)n2 * 4);
    int*   blk_sum  = (int*)alloc((size_t)1024 * 4);
    __half* Wt1     = (__half*)alloc((size_t)128 * 128 * 2);
    __half* Wt2     = (__half*)alloc((size_t)128 * 128 * 2);
    __half* Wt3     = (__half*)alloc((size_t)64 * 128 * 2);
    int*   col_idx  = (int*)alloc((size_t)E * 4);
    // hA region also hosts the 2 packed partition arrays (E*4 + E = 8 MB <= 25.6 MB)
    __half* hA      = (__half*)alloc((size_t)N * NFEAT * 2);
    __half* hB      = (__half*)alloc((size_t)N * NFEAT * 2);
    unsigned int*  dstP = (unsigned int*)hA;
    unsigned char* srcB = (unsigned char*)(dstP + E);

    // --- weight transpose/convert (independent of graph chain) ---
    wt_all_kernel<<<320, 128, 0, stream>>>(W1, W2, W3, Wt1, Wt2, Wt3);

    // --- CSR build: hist -> scan(concat) -> scatter -> bucket ---
    hist_kernel<<<nblk, 256, 0, stream>>>(src, dst, hist2, NB, nblk, nh, E);
    scan1_kernel<<<nsb, 256, 0, stream>>>(hist2, blk_sum, n2);
    scan2_kernel<<<1, 1024, 0, stream>>>(blk_sum, nsb);
    scan3_kernel<<<nsb, 256, 0, stream>>>(hist2, blk_sum, n2);
    scatter_kernel<<<nblk, 256, 0, stream>>>(src, dst, hist2, dstP, srcB, NB, nblk, nh, E);
    bucket_kernel<<<NB, 256, 0, stream>>>(dstP, srcB, hist2, row_ptr, col_idx,
                                          in_norm, out_norm, N, NB, nblk, nh, E);

    const int gb = (N + 63) / 64;
    // layer 1 (x fp32 -> h fp16)
    mfma_gemm_kernel<128, float><<<gb, 256, 0, stream>>>(feat, Wt1, out_norm, hA, N);
    agg_kernel<128, true, __half><<<(N + 15) / 16, 256, 0, stream>>>(hA, row_ptr, col_idx,
                                                                     in_norm, b1, hB, N);
    // layer 2 (fp16 -> fp16)
    mfma_gemm_kernel<128, __half><<<gb, 256, 0, stream>>>(hB, Wt2, out_norm, hA, N);
    agg_kernel<128, true, __half><<<(N + 15) / 16, 256, 0, stream>>>(hA, row_ptr, col_idx,
                                                                     in_norm, b2, hB, N);
    // layer 3 (fp16 -> fp32 d_out, no relu)
    mfma_gemm_kernel<64, __half><<<gb, 256, 0, stream>>>(hB, Wt3, out_norm, hA, N);
    agg_kernel<64, false, float><<<(N + 31) / 32, 256, 0, stream>>>(hA, row_ptr, col_idx,
                                                                    in_norm, b3, (float*)d_out, N);
}

// Round 8
// 345.924 us; speedup vs baseline: 2.0388x; 1.0325x over previous
//
#include <hip/hip_runtime.h>
#include <hip/hip_fp16.h>

// ---------------------------------------------------------------------------
// GCNEncoder: 3-layer GCN with symmetric norm and self-loops.
//   per layer: h = (x * out_norm) @ W ; agg = segsum(h[src], dst) + h (self)
//              out = agg * in_norm + b ; relu (layers 1,2)
// CSR build (by dst) -> aggregation is pure gather.
// R2: FAILED — device atomics have a ~20 G/s write-through floor.
// R3: LDS-atomic radix partition (zero device atomics).
// R4: inter-layer tables fp16 (256 B gather rows, ~L2-resident).
// R5: GEMMs on MFMA (v_mfma_f32_16x16x32_f16), W pre-transposed fp16.
// R6: packed scatter payloads + single concatenated hist scan.
// R7: scatter_kernel does a block-local LDS counting sort and streams runs
//     out coalesced — kills the partial-line RMW write amplification.
// ---------------------------------------------------------------------------

#define NFEAT 128
#define BBITS 8
#define BSZ 256                     // nodes per bucket
#define EPB 4096                    // edges per partition block

union H8 { float4 f4; __half2 h2[4]; };   // 8 halves = 16 B

using half8v = __attribute__((ext_vector_type(8))) _Float16;
using f32x4  = __attribute__((ext_vector_type(4))) float;

// --- Pass 1: per-block LDS histograms; hist2 = [D part | S part], bucket-major ---
__global__ __launch_bounds__(256) void hist_kernel(const int* __restrict__ src,
                                                   const int* __restrict__ dst,
                                                   int* __restrict__ hist2,
                                                   int NB, int nblk, int nh, int E) {
    __shared__ int hd[512], hs[512];
    const int t = threadIdx.x, b = blockIdx.x;
    for (int u = t; u < 512; u += 256) { hd[u] = 0; hs[u] = 0; }
    __syncthreads();
    const int base4 = b * (EPB / 4);
    #pragma unroll
    for (int j = 0; j < 4; ++j) {
        int i4 = base4 + j * 256 + t;
        int e0 = i4 * 4;
        if (e0 + 3 < E) {
            int4 s = ((const int4*)src)[i4];
            int4 d = ((const int4*)dst)[i4];
            atomicAdd(&hs[s.x >> BBITS], 1); atomicAdd(&hs[s.y >> BBITS], 1);
            atomicAdd(&hs[s.z >> BBITS], 1); atomicAdd(&hs[s.w >> BBITS], 1);
            atomicAdd(&hd[d.x >> BBITS], 1); atomicAdd(&hd[d.y >> BBITS], 1);
            atomicAdd(&hd[d.z >> BBITS], 1); atomicAdd(&hd[d.w >> BBITS], 1);
        } else {
            for (int e = e0; e < E && e < e0 + 4; ++e) {
                atomicAdd(&hs[src[e] >> BBITS], 1);
                atomicAdd(&hd[dst[e] >> BBITS], 1);
            }
        }
    }
    __syncthreads();
    for (int u = t; u < NB; u += 256) {
        hist2[u * nblk + b]      = hd[u];
        hist2[nh + u * nblk + b] = hs[u];
    }
}

// --- 3-kernel exclusive scan, 2 elements/thread (512/block), in-place ---
__global__ __launch_bounds__(256) void scan1_kernel(int* __restrict__ data,
                                                    int* __restrict__ blk_sum, int n) {
    const int tid = threadIdx.x, lane = tid & 63, wid = tid >> 6;  // 4 waves
    const int i2 = blockIdx.x * 256 + tid;
    int a = 0, b = 0;
    if (2 * i2 + 1 < n)      { int2 v = ((const int2*)data)[i2]; a = v.x; b = v.y; }
    else if (2 * i2 < n)     { a = data[2 * i2]; }
    int s = a + b;
    int incl = s;
    #pragma unroll
    for (int off = 1; off < 64; off <<= 1) {
        int t2 = __shfl_up(incl, off, 64);
        if (lane >= off) incl += t2;
    }
    __shared__ int ws[4];
    if (lane == 63) ws[wid] = incl;
    __syncthreads();
    int woff = 0;
    #pragma unroll
    for (int w = 0; w < 3; ++w) if (w < wid) woff += ws[w];
    int pref = woff + incl - s;
    if (2 * i2 < n)     data[2 * i2]     = pref;
    if (2 * i2 + 1 < n) data[2 * i2 + 1] = pref + a;
    if (tid == 0) blk_sum[blockIdx.x] = ws[0] + ws[1] + ws[2] + ws[3];
}

__global__ __launch_bounds__(1024) void scan2_kernel(int* __restrict__ blk, int nb) {
    const int tid = threadIdx.x, lane = tid & 63, wid = tid >> 6;  // 16 waves
    int v = (tid < nb) ? blk[tid] : 0;
    int incl = v;
    #pragma unroll
    for (int off = 1; off < 64; off <<= 1) {
        int t = __shfl_up(incl, off, 64);
        if (lane >= off) incl += t;
    }
    __shared__ int ws[16];
    if (lane == 63) ws[wid] = incl;
    __syncthreads();
    int woff = 0;
    #pragma unroll
    for (int w = 0; w < 15; ++w) if (w < wid) woff += ws[w];
    if (tid < nb) blk[tid] = woff + incl - v;
}

__global__ __launch_bounds__(256) void scan3_kernel(int* __restrict__ data,
                                                    const int* __restrict__ blk, int n) {
    const int i2 = blockIdx.x * 256 + threadIdx.x;
    int add = blk[blockIdx.x];
    if (2 * i2 < n)     data[2 * i2]     += add;
    if (2 * i2 + 1 < n) data[2 * i2 + 1] += add;
}

// --- Pass 2: scatter via block-local LDS counting sort -> coalesced run writes ---
// 512 threads, 8 edges/thread. Payloads: dstP = dst_local<<24|src ; srcB = src_local.
__global__ __launch_bounds__(512) void scatter_kernel(const int* __restrict__ src,
                                                      const int* __restrict__ dst,
                                                      const int* __restrict__ hist2,
                                                      unsigned int* __restrict__ dstP,
                                                      unsigned char* __restrict__ srcB,
                                                      int NB, int nblk, int nh, int E) {
    __shared__ int hd[512], hs[512], startD[512], startS[512], baseD[512], baseS[512];
    __shared__ int ws[8];
    __shared__ unsigned int   payD[EPB];   // 16 KB
    __shared__ unsigned short kD[EPB];     // 8 KB
    __shared__ unsigned char  sV[EPB];     // 4 KB
    __shared__ unsigned short kS[EPB];     // 8 KB
    const int t = threadIdx.x, b = blockIdx.x;
    const int lane = t & 63, wid = t >> 6;                 // 8 waves
    hd[t] = 0; hs[t] = 0;
    for (int u = t; u < NB; u += 512) {
        baseD[u] = hist2[u * nblk + b];
        baseS[u] = hist2[nh + u * nblk + b] - E;           // S scanned after D (sum D = E)
    }
    __syncthreads();

    const int e0 = b * EPB;
    const int nE = min(EPB, E - e0);                       // edges this block
    int se[8], de[8], rD[8], rS[8];
    const int be = e0 + t * 8;
    if (be + 7 < E) {
        int4 s0 = ((const int4*)src)[(be >> 2)];
        int4 s1 = ((const int4*)src)[(be >> 2) + 1];
        int4 d0 = ((const int4*)dst)[(be >> 2)];
        int4 d1 = ((const int4*)dst)[(be >> 2) + 1];
        se[0]=s0.x; se[1]=s0.y; se[2]=s0.z; se[3]=s0.w;
        se[4]=s1.x; se[5]=s1.y; se[6]=s1.z; se[7]=s1.w;
        de[0]=d0.x; de[1]=d0.y; de[2]=d0.z; de[3]=d0.w;
        de[4]=d1.x; de[5]=d1.y; de[6]=d1.z; de[7]=d1.w;
    } else {
        #pragma unroll
        for (int j = 0; j < 8; ++j) {
            se[j] = (be + j < E) ? src[be + j] : 0;
            de[j] = (be + j < E) ? dst[be + j] : 0;
        }
    }
    #pragma unroll
    for (int j = 0; j < 8; ++j) {
        if (be + j < E) {
            rD[j] = atomicAdd(&hd[de[j] >> BBITS], 1);
            rS[j] = atomicAdd(&hs[se[j] >> BBITS], 1);
        }
    }
    __syncthreads();
    // exclusive scan hd -> startD (512 entries, 1/thread, 8 waves)
    {
        int v = hd[t], incl = v;
        #pragma unroll
        for (int o = 1; o < 64; o <<= 1) {
            int x = __shfl_up(incl, o, 64);
            if (lane >= o) incl += x;
        }
        if (lane == 63) ws[wid] = incl;
        __syncthreads();
        int woff = 0;
        #pragma unroll
        for (int w = 0; w < 7; ++w) if (w < wid) woff += ws[w];
        startD[t] = woff + incl - v;
    }
    __syncthreads();
    {
        int v = hs[t], incl = v;
        #pragma unroll
        for (int o = 1; o < 64; o <<= 1) {
            int x = __shfl_up(incl, o, 64);
            if (lane >= o) incl += x;
        }
        if (lane == 63) ws[wid] = incl;
        __syncthreads();
        int woff = 0;
        #pragma unroll
        for (int w = 0; w < 7; ++w) if (w < wid) woff += ws[w];
        startS[t] = woff + incl - v;
    }
    __syncthreads();
    // place into LDS, sorted by bucket
    #pragma unroll
    for (int j = 0; j < 8; ++j) {
        if (be + j < E) {
            int kd = de[j] >> BBITS;
            int p  = startD[kd] + rD[j];
            payD[p] = ((unsigned int)(de[j] & (BSZ - 1)) << 24) | (unsigned int)se[j];
            kD[p]   = (unsigned short)kd;
            int ks = se[j] >> BBITS;
            int q  = startS[ks] + rS[j];
            sV[q] = (unsigned char)(se[j] & (BSZ - 1));
            kS[q] = (unsigned short)ks;
        }
    }
    __syncthreads();
    // stream out: consecutive slots -> consecutive global addresses within runs
    for (int p = t; p < nE; p += 512) {
        int k = kD[p];
        dstP[baseD[k] + (p - startD[k])] = payD[p];
        int k2 = kS[p];
        srcB[baseS[k2] + (p - startS[k2])] = sV[p];
    }
}

// --- Pass 3: per-bucket CSR finalize + degrees + norms (all LDS) ---
__global__ __launch_bounds__(256) void bucket_kernel(const unsigned int* __restrict__ dstP,
                                                     const unsigned char* __restrict__ srcB,
                                                     const int* __restrict__ hist2,
                                                     int* __restrict__ row_ptr,
                                                     int* __restrict__ col_idx,
                                                     float* __restrict__ in_norm,
                                                     float* __restrict__ out_norm,
                                                     int N, int NB, int nblk, int nh, int E) {
    __shared__ int cnt[BSZ], scnt[BSZ], start[BSZ], off[BSZ];
    __shared__ int ws[4];
    const int k = blockIdx.x, t = threadIdx.x;
    const int node0 = k << BBITS;
    cnt[t] = 0; scnt[t] = 0; off[t] = 0;
    __syncthreads();
    const int bB = hist2[k * nblk];
    const int bE = (k + 1 < NB) ? hist2[(k + 1) * nblk] : E;
    const int sB = hist2[nh + k * nblk] - E;
    const int sE = ((k + 1 < NB) ? hist2[nh + (k + 1) * nblk] : 2 * E) - E;
    for (int i = bB + t; i < bE; i += 256) atomicAdd(&cnt[dstP[i] >> 24], 1);
    for (int i = sB + t; i < sE; i += 256) atomicAdd(&scnt[srcB[i]], 1);
    __syncthreads();
    const int lane = t & 63, wid = t >> 6;
    int v = cnt[t];
    int incl = v;
    #pragma unroll
    for (int o = 1; o < 64; o <<= 1) {
        int x = __shfl_up(incl, o, 64);
        if (lane >= o) incl += x;
    }
    if (lane == 63) ws[wid] = incl;
    __syncthreads();
    int woff = 0;
    #pragma unroll
    for (int w = 0; w < 3; ++w) if (w < wid) woff += ws[w];
    start[t] = woff + incl - v;
    {
        int node = node0 + t;
        if (node < N) {
            row_ptr[node] = bB + start[t];
            in_norm[node]  = rsqrtf((float)(v + 1));          // +1 self-loop
            out_norm[node] = rsqrtf((float)(scnt[t] + 1));
        }
    }
    if (k == 0 && t == 0) row_ptr[N] = E;
    __syncthreads();
    for (int i = bB + t; i < bE; i += 256) {
        unsigned int pv = dstP[i];
        int local = pv >> 24;
        int r = atomicAdd(&off[local], 1);
        col_idx[bB + start[local] + r] = (int)(pv & 0xFFFFFFu);
    }
}

// --- all three W [K][Ncols] fp32 -> Wt [Ncols][K=128] fp16 in one launch ---
__global__ void wt_all_kernel(const float* __restrict__ W1, const float* __restrict__ W2,
                              const float* __restrict__ W3, __half* __restrict__ Wt1,
                              __half* __restrict__ Wt2, __half* __restrict__ Wt3) {
    int b = blockIdx.x, k = threadIdx.x;
    if (b < 128)      Wt1[b * 128 + k] = __float2half(W1[k * 128 + b]);
    else if (b < 256) { int n = b - 128; Wt2[n * 128 + k] = __float2half(W2[k * 128 + n]); }
    else              { int n = b - 256; Wt3[n * 128 + k] = __float2half(W3[k * 64 + n]); }
}

// --- MFMA GEMM: h[64 rows x BN] = fp16(x * out_norm) @ W, K = 128 ---
template <int BN, typename XT>
__global__ __launch_bounds__(256) void mfma_gemm_kernel(const XT* __restrict__ x,
                                                        const __half* __restrict__ Wt,
                                                        const float* __restrict__ out_norm,
                                                        __half* __restrict__ h, int n_rows) {
    constexpr int BM = 64;
    constexpr int NT = BN / 16;          // 8 (BN=128) or 4 (BN=64)
    __shared__ __half As[BM][136];
    __shared__ __half Bs[BN][136];
    const int tid  = threadIdx.x;
    const int row0 = blockIdx.x * BM;

    {
        int r  = tid >> 2;                 // 0..63
        int c0 = (tid & 3) * 32;           // 0,32,64,96
        int grow = row0 + r;
        if (grow < n_rows) {
            float norm = out_norm[grow];
            if constexpr (sizeof(XT) == 4) {
                const float* xp = (const float*)x + (size_t)grow * NFEAT + c0;
                #pragma unroll
                for (int j = 0; j < 4; ++j) {
                    float4 p0 = *(const float4*)(xp + j * 8);
                    float4 p1 = *(const float4*)(xp + j * 8 + 4);
                    H8 u;
                    u.h2[0] = __floats2half2_rn(p0.x * norm, p0.y * norm);
                    u.h2[1] = __floats2half2_rn(p0.z * norm, p0.w * norm);
                    u.h2[2] = __floats2half2_rn(p1.x * norm, p1.y * norm);
                    u.h2[3] = __floats2half2_rn(p1.z * norm, p1.w * norm);
                    *(float4*)&As[r][c0 + j * 8] = u.f4;
                }
            } else {
                const __half* xp = (const __half*)x + (size_t)grow * NFEAT + c0;
                #pragma unroll
                for (int j = 0; j < 4; ++j) {
                    H8 u; u.f4 = *(const float4*)(xp + j * 8);
                    #pragma unroll
                    for (int q = 0; q < 4; ++q) {
                        float2 p = __half22float2(u.h2[q]);
                        u.h2[q] = __floats2half2_rn(p.x * norm, p.y * norm);
                    }
                    *(float4*)&As[r][c0 + j * 8] = u.f4;
                }
            }
        } else {
            H8 z; z.f4 = make_float4(0.f, 0.f, 0.f, 0.f);
            #pragma unroll
            for (int j = 0; j < 4; ++j) *(float4*)&As[r][c0 + j * 8] = z.f4;
        }
    }
    {
        constexpr int TPR = 256 / BN;              // threads per row: 2 or 4
        constexpr int CH  = 128 / TPR;             // halves per thread: 64 or 32
        int wr = tid / TPR;
        int wc = (tid % TPR) * CH;
        const __half* wp = Wt + wr * 128 + wc;
        #pragma unroll
        for (int j = 0; j < CH / 8; ++j)
            *(float4*)&Bs[wr][wc + j * 8] = *(const float4*)(wp + j * 8);
    }
    __syncthreads();

    const int lane = tid & 63, wid = tid >> 6;
    const int lr = lane & 15, quad = lane >> 4;
    const int koff = quad * 8;
    f32x4 acc[NT];
    #pragma unroll
    for (int t = 0; t < NT; ++t) acc[t] = (f32x4){0.f, 0.f, 0.f, 0.f};

    #pragma unroll
    for (int ks = 0; ks < 4; ++ks) {
        half8v a = *(const half8v*)&As[wid * 16 + lr][ks * 32 + koff];
        #pragma unroll
        for (int nt = 0; nt < NT; ++nt) {
            half8v b = *(const half8v*)&Bs[nt * 16 + lr][ks * 32 + koff];
            acc[nt] = __builtin_amdgcn_mfma_f32_16x16x32_f16(a, b, acc[nt], 0, 0, 0);
        }
    }

    #pragma unroll
    for (int nt = 0; nt < NT; ++nt) {
        #pragma unroll
        for (int r = 0; r < 4; ++r) {
            int row = row0 + wid * 16 + quad * 4 + r;
            if (row < n_rows)
                h[(size_t)row * BN + nt * 16 + lr] = __float2half(acc[nt][r]);
        }
    }
}

// Gather aggregation + epilogue: out = (sum_in h[src] + h[node]) * in_norm + b [, relu]
template <int DOUT, bool RELU, typename OutT>
__global__ __launch_bounds__(256) void agg_kernel(const __half* __restrict__ h,
                                                  const int* __restrict__ row_ptr,
                                                  const int* __restrict__ col_idx,
                                                  const float* __restrict__ in_norm,
                                                  const float* __restrict__ bias,
                                                  OutT* __restrict__ out, int n) {
    constexpr int TPN = DOUT / 8;      // threads per node (8 halves = 16 B each)
    constexpr int NPB = 256 / TPN;     // nodes per block
    const int tid  = threadIdx.x;
    const int sub  = tid / TPN;
    const int c    = (tid % TPN) * 8;
    const int node = blockIdx.x * NPB + sub;
    if (node >= n) return;

    float acc[8];
    {
        H8 u; u.f4 = *(const float4*)(h + (size_t)node * DOUT + c);  // self-loop
        #pragma unroll
        for (int q = 0; q < 4; ++q) {
            float2 p = __half22float2(u.h2[q]);
            acc[q * 2] = p.x; acc[q * 2 + 1] = p.y;
        }
    }
    int e  = row_ptr[node];
    int e1 = row_ptr[node + 1];
    for (; e + 3 < e1; e += 4) {
        int s0 = col_idx[e], s1 = col_idx[e + 1], s2 = col_idx[e + 2], s3 = col_idx[e + 3];
        H8 u0, u1, u2, u3;
        u0.f4 = *(const float4*)(h + (size_t)s0 * DOUT + c);
        u1.f4 = *(const float4*)(h + (size_t)s1 * DOUT + c);
        u2.f4 = *(const float4*)(h + (size_t)s2 * DOUT + c);
        u3.f4 = *(const float4*)(h + (size_t)s3 * DOUT + c);
        #pragma unroll
        for (int q = 0; q < 4; ++q) {
            float2 p0 = __half22float2(u0.h2[q]);
            float2 p1 = __half22float2(u1.h2[q]);
            float2 p2 = __half22float2(u2.h2[q]);
            float2 p3 = __half22float2(u3.h2[q]);
            acc[q * 2]     += (p0.x + p1.x) + (p2.x + p3.x);
            acc[q * 2 + 1] += (p0.y + p1.y) + (p2.y + p3.y);
        }
    }
    for (; e < e1; ++e) {
        int s0 = col_idx[e];
        H8 u0; u0.f4 = *(const float4*)(h + (size_t)s0 * DOUT + c);
        #pragma unroll
        for (int q = 0; q < 4; ++q) {
            float2 p0 = __half22float2(u0.h2[q]);
            acc[q * 2] += p0.x; acc[q * 2 + 1] += p0.y;
        }
    }
    float inn = in_norm[node];
    float r[8];
    #pragma unroll
    for (int q = 0; q < 8; ++q) {
        r[q] = acc[q] * inn + bias[c + q];
        if (RELU) r[q] = fmaxf(r[q], 0.0f);
    }
    if constexpr (sizeof(OutT) == 2) {
        H8 o;
        #pragma unroll
        for (int q = 0; q < 4; ++q) o.h2[q] = __floats2half2_rn(r[q * 2], r[q * 2 + 1]);
        *(float4*)((__half*)out + (size_t)node * DOUT + c) = o.f4;
    } else {
        float4 o0, o1;
        o0.x=r[0]; o0.y=r[1]; o0.z=r[2]; o0.w=r[3];
        o1.x=r[4]; o1.y=r[5]; o1.z=r[6]; o1.w=r[7];
        *(float4*)((float*)out + (size_t)node * DOUT + c)     = o0;
        *(float4*)((float*)out + (size_t)node * DOUT + c + 4) = o1;
    }
}

extern "C" void kernel_launch(void* const* d_in, const int* in_sizes, int n_in,
                              void* d_out, int out_size, void* d_ws, size_t ws_size,
                              hipStream_t stream) {
    const float* feat = (const float*)d_in[0];
    const int*   src  = (const int*)d_in[1];
    const int*   dst  = (const int*)d_in[2];
    const float* W1   = (const float*)d_in[3];
    const float* b1   = (const float*)d_in[4];
    const float* W2   = (const float*)d_in[5];
    const float* b2   = (const float*)d_in[6];
    const float* W3   = (const float*)d_in[7];
    const float* b3   = (const float*)d_in[8];

    const int N = in_sizes[0] / NFEAT;   // 100000
    const int E = in_sizes[1];           // 1600000

    const int NB   = (N + BSZ - 1) / BSZ;        // 391 buckets
    const int nblk = (E + EPB - 1) / EPB;        // 391 partition blocks
    const int nh   = NB * nblk;                  // hist elements per side
    const int n2   = 2 * nh;                     // concatenated [D|S]
    const int nsb  = (n2 + 511) / 512;           // scan blocks (<= 1024)

    char* ws = (char*)d_ws;
    auto alloc = [&](size_t bytes) {
        char* p = ws;
        ws += (bytes + 255) & ~(size_t)255;
        return p;
    };
    float* out_norm = (float*)alloc((size_t)N * 4);
    float* in_norm  = (float*)alloc((size_t)N * 4);
    int*   row_ptr  = (int*)alloc((size_t)(N + 1) * 4);
    int*   hist2    = (int*)alloc((size_t)n2 * 4);
    int*   blk_sum  = (int*)alloc((size_t)1024 * 4);
    __half* Wt1     = (__half*)alloc((size_t)128 * 128 * 2);
    __half* Wt2     = (__half*)alloc((size_t)128 * 128 * 2);
    __half* Wt3     = (__half*)alloc((size_t)64 * 128 * 2);
    int*   col_idx  = (int*)alloc((size_t)E * 4);
    // hA region also hosts the 2 packed partition arrays (E*4 + E = 8 MB <= 25.6 MB)
    __half* hA      = (__half*)alloc((size_t)N * NFEAT * 2);
    __half* hB      = (__half*)alloc((size_t)N * NFEAT * 2);
    unsigned int*  dstP = (unsigned int*)hA;
    unsigned char* srcB = (unsigned char*)(dstP + E);

    // --- weight transpose/convert (independent of graph chain) ---
    wt_all_kernel<<<320, 128, 0, stream>>>(W1, W2, W3, Wt1, Wt2, Wt3);

    // --- CSR build: hist -> scan(concat) -> scatter(LDS sort) -> bucket ---
    hist_kernel<<<nblk, 256, 0, stream>>>(src, dst, hist2, NB, nblk, nh, E);
    scan1_kernel<<<nsb, 256, 0, stream>>>(hist2, blk_sum, n2);
    scan2_kernel<<<1, 1024, 0, stream>>>(blk_sum, nsb);
    scan3_kernel<<<nsb, 256, 0, stream>>>(hist2, blk_sum, n2);
    scatter_kernel<<<nblk, 512, 0, stream>>>(src, dst, hist2, dstP, srcB, NB, nblk, nh, E);
    bucket_kernel<<<NB, 256, 0, stream>>>(dstP, srcB, hist2, row_ptr, col_idx,
                                          in_norm, out_norm, N, NB, nblk, nh, E);

    const int gb = (N + 63) / 64;
    // layer 1 (x fp32 -> h fp16)
    mfma_gemm_kernel<128, float><<<gb, 256, 0, stream>>>(feat, Wt1, out_norm, hA, N);
    agg_kernel<128, true, __half><<<(N + 15) / 16, 256, 0, stream>>>(hA, row_ptr, col_idx,
                                                                     in_norm, b1, hB, N);
    // layer 2 (fp16 -> fp16)
    mfma_gemm_kernel<128, __half><<<gb, 256, 0, stream>>>(hB, Wt2, out_norm, hA, N);
    agg_kernel<128, true, __half><<<(N + 15) / 16, 256, 0, stream>>>(hA, row_ptr, col_idx,
                                                                     in_norm, b2, hB, N);
    // layer 3 (fp16 -> fp32 d_out, no relu)
    mfma_gemm_kernel<64, __half><<<gb, 256, 0, stream>>>(hB, Wt3, out_norm, hA, N);
    agg_kernel<64, false, float><<<(N + 31) / 32, 256, 0, stream>>>(hA, row_ptr, col_idx,
                                                                    in_norm, b3, (float*)d_out, N);
}